// Round 3
// baseline (9265.371 us; speedup 1.0000x reference)
//
#include <hip/hip_runtime.h>
#include <math.h>

#define NT_ 8000
#define MT_ 16000
#define NA_ 25000
#define MA_ 50000
#define NROOT_ 256

// ---------------------------------------------------------------------------
// Feature descriptor: evaluates fz/fr/fh rows on the fly (all tables f32).
//   value(m,n) = bias[n] + dtab[didx[m*dstride]][n]
//              + otab[oidx0[m*os0]+oo0][n] (+ oidx1 term) (+ oidx2 term)
// ---------------------------------------------------------------------------
struct Feat {
  const float* dtab; const int* didx; int dstride;
  const float* otab;
  const int* oidx0; int os0; int oo0;
  const int* oidx1; int os1; int oo1;
  const int* oidx2; int os2; int oo2;
  const float* bias;
};

__device__ __forceinline__ float sigm(float x){ return 1.0f/(1.0f+expf(-x)); }

__device__ __forceinline__ float feat_eval(const Feat& f, int m, int n){
  float v = 0.0f;
  if (f.bias) v += f.bias[n];
  if (f.dtab) v += f.dtab[(size_t)f.didx[(size_t)m*f.dstride]*256 + n];
  if (f.otab){
    v += f.otab[((size_t)(f.oidx0[(size_t)m*f.os0]+f.oo0))*256 + n];
    if (f.oidx1) v += f.otab[((size_t)(f.oidx1[(size_t)m*f.os1]+f.oo1))*256 + n];
    if (f.oidx2) v += f.otab[((size_t)(f.oidx2[(size_t)m*f.os2]+f.oo2))*256 + n];
  }
  return v;
}

// ---------------------------------------------------------------------------
__global__ void k_zero(float* __restrict__ p, size_t n){
  size_t i = (size_t)blockIdx.x*blockDim.x + threadIdx.x;
  size_t st = (size_t)gridDim.x*blockDim.x;
  for (; i<n; i+=st) p[i] = 0.0f;
}

__global__ void k_aidx(const int* __restrict__ g_fnode, const int* __restrict__ g_fmess,
                       int* __restrict__ aidx, int M){
  int m = blockIdx.x*blockDim.x + threadIdx.x;
  if (m<M) aidx[m] = g_fnode[g_fmess[(size_t)m*4]];
}

// dst[m][c] = tab[idx[m*istride]][c]
__global__ void k_gather_f32(const float* __restrict__ tab, const int* __restrict__ idx,
                             int istride, float* __restrict__ dst, int M){
  int m = blockIdx.x; int c = threadIdx.x;
  dst[(size_t)m*256+c] = tab[(size_t)idx[(size_t)m*istride]*256 + c];
}

// dst[m][c] = sum_j src[idx[(rowsel?rowsel[m]:m)*istride + j]][c]
__global__ void k_gather_sum(const float* __restrict__ src, const int* __restrict__ idx,
                             const int* __restrict__ rowsel, int J, int istride,
                             float* __restrict__ dst, int M){
  int m = blockIdx.x; int c = threadIdx.x;
  int r = rowsel ? rowsel[m] : m;
  float s = 0.0f;
  for (int j=0;j<J;j++){
    int id = idx[(size_t)r*istride + j];
    s += src[(size_t)id*256 + c];
  }
  dst[(size_t)m*256+c] = s;
}

// ---------------------------------------------------------------------------
// dual_gemm: C = epilogue(A1@B1 [+ A2@B2]).  K=256, N=256 fixed. All f32.
// MODE 0: C = A1@B1
// MODE 1: C = relu(A1@B1 [+A2@B2] + feat(f1));  row0 zeroed if mask0
// MODE 2: C = tanh(A1@B1 + A2@B2 + feat(f1))
// ---------------------------------------------------------------------------
template<int NG, int MODE>
__global__ __launch_bounds__(256)
void dual_gemm(const float* __restrict__ A1, const float* __restrict__ B1,
               const float* __restrict__ A2, const float* __restrict__ B2,
               float* __restrict__ Cf, float* __restrict__ Co,
               int M, Feat f1, int mask0)
{
  __shared__ float As1[16][68];
  __shared__ float Bs1[16][68];
  __shared__ float As2[NG>1?16:1][NG>1?68:4];
  __shared__ float Bs2[NG>1?16:1][NG>1?68:4];
  const int tid = threadIdx.x;
  const int bm = blockIdx.x<<6, bn = blockIdx.y<<6;
  const int tm = ((tid>>4)&15)<<2;
  const int tn = (tid&15)<<2;
  const int lm   = tid>>2;        // A-load row within tile (0..63)
  const int lk4  = (tid&3)<<2;    // A-load k offset (0,4,8,12)
  const int lbk  = tid>>4;        // B-load k row (0..15)
  const int lbn4 = (tid&15)<<2;   // B-load n offset
  float acc1[4][4]={}, acc2[4][4]={};
  const int arow = bm + lm;
  const bool aval = (arow < M);

  for (int k0=0;k0<256;k0+=16){
    float4 a1v = make_float4(0,0,0,0), a2v = make_float4(0,0,0,0);
    if (aval) a1v = *(const float4*)(A1 + (size_t)arow*256 + k0 + lk4);
    if (NG>1 && aval) a2v = *(const float4*)(A2 + (size_t)arow*256 + k0 + lk4);
    float4 b1r = *(const float4*)(B1 + (size_t)(k0+lbk)*256 + bn + lbn4);
    float4 b2r = make_float4(0,0,0,0);
    if (NG>1) b2r = *(const float4*)(B2 + (size_t)(k0+lbk)*256 + bn + lbn4);
    __syncthreads();
    As1[lk4+0][lm]=a1v.x; As1[lk4+1][lm]=a1v.y; As1[lk4+2][lm]=a1v.z; As1[lk4+3][lm]=a1v.w;
    *(float4*)&Bs1[lbk][lbn4] = b1r;
    if (NG>1){
      As2[lk4+0][lm]=a2v.x; As2[lk4+1][lm]=a2v.y; As2[lk4+2][lm]=a2v.z; As2[lk4+3][lm]=a2v.w;
      *(float4*)&Bs2[lbk][lbn4] = b2r;
    }
    __syncthreads();
    #pragma unroll
    for (int k=0;k<16;k++){
      float a1r[4], b1v[4];
      #pragma unroll
      for (int i=0;i<4;i++){ a1r[i]=As1[k][tm+i]; b1v[i]=Bs1[k][tn+i]; }
      #pragma unroll
      for (int i=0;i<4;i++)
        #pragma unroll
        for (int j=0;j<4;j++)
          acc1[i][j] = fmaf(a1r[i], b1v[j], acc1[i][j]);
      if (NG>1){
        float a2r[4], b2v[4];
        #pragma unroll
        for (int i=0;i<4;i++){ a2r[i]=As2[k][tm+i]; b2v[i]=Bs2[k][tn+i]; }
        #pragma unroll
        for (int i=0;i<4;i++)
          #pragma unroll
          for (int j=0;j<4;j++)
            acc2[i][j] = fmaf(a2r[i], b2v[j], acc2[i][j]);
      }
    }
  }

  #pragma unroll
  for (int i=0;i<4;i++){
    int row = bm + tm + i;
    if (row >= M) continue;
    #pragma unroll
    for (int j=0;j<4;j++){
      int col = bn + tn + j;
      float v;
      if (MODE==0){
        v = acc1[i][j];
      } else if (MODE==1){
        v = acc1[i][j]; if (NG>1) v += acc2[i][j];
        v += feat_eval(f1, row, col);
        v = fmaxf(v, 0.0f);
        if (mask0 && row==0) v = 0.0f;
      } else {
        float s = acc1[i][j] + (NG>1?acc2[i][j]:0.0f) + feat_eval(f1,row,col);
        v = tanhf(s);
      }
      if (Cf) Cf[(size_t)row*256+col] = v;
      if (Co) Co[(size_t)row*256+col] = v;
    }
  }
}

// ---------------------------------------------------------------------------
// Fused GRU step: per 32-row message tile, gather sum_h / sum_gh on the fly
// (r-gate sigmoid inline), GEMM against Wz_h / Wh_h, full GRU epilogue.
// BN = 256 (full width) so gathers happen exactly once per element.
// ---------------------------------------------------------------------------
__global__ __launch_bounds__(256)
void gru_fused(const float* __restrict__ cur, const float* __restrict__ hU,
               const int* __restrict__ bgraph,
               const float* __restrict__ Wzh, const float* __restrict__ Whh,
               Feat fz, Feat fr, Feat fh,
               float* __restrict__ nxt, int M)
{
  __shared__ float sh [32][258];
  __shared__ float sgh[32][18];
  __shared__ float Bz [16][256];
  __shared__ float Bh [16][256];
  __shared__ int   bgl[32][6];
  const int tid = threadIdx.x;
  const int bm  = blockIdx.x<<5;

  if (tid < 192){
    int r = tid/6, j = tid - r*6;
    int m = bm + r;
    bgl[r][j] = (m<M) ? bgraph[(size_t)m*6+j] : 0;
  }
  __syncthreads();

  const int tc = tid & 31, tr = tid >> 5;       // compute: 4 rows x 8 cols each
  const int sr = tid >> 3, sk = (tid & 7) << 1; // stage: 32 rows x 8 thr, 2 cols
  const int mS = bm + sr;
  const int kb = tid>>4, cb = (tid&15)<<4;      // B stage: 16 rows x 16 thr
  float acc1[4][8]={}, acc2[4][8]={};

  for (int k0=0;k0<256;k0+=16){
    { // stage B tiles (f32)
      const float* pz = Wzh + (size_t)(k0+kb)*256 + cb;
      const float* ph = Whh + (size_t)(k0+kb)*256 + cb;
      *(float4*)&Bz[kb][cb+ 0] = *(const float4*)(pz+ 0);
      *(float4*)&Bz[kb][cb+ 4] = *(const float4*)(pz+ 4);
      *(float4*)&Bz[kb][cb+ 8] = *(const float4*)(pz+ 8);
      *(float4*)&Bz[kb][cb+12] = *(const float4*)(pz+12);
      *(float4*)&Bh[kb][cb+ 0] = *(const float4*)(ph+ 0);
      *(float4*)&Bh[kb][cb+ 4] = *(const float4*)(ph+ 4);
      *(float4*)&Bh[kb][cb+ 8] = *(const float4*)(ph+ 8);
      *(float4*)&Bh[kb][cb+12] = *(const float4*)(ph+12);
    }
    { // stage gathered sums
      float s0=0,s1=0,g0=0,g1=0;
      if (mS < M){
        float fr0 = feat_eval(fr, mS, k0+sk);
        float fr1 = feat_eval(fr, mS, k0+sk+1);
        #pragma unroll
        for (int j=0;j<6;j++){
          int id = bgl[sr][j];
          float2 hv = *(const float2*)(cur + (size_t)id*256 + k0 + sk);
          float2 hu = *(const float2*)(hU  + (size_t)id*256 + k0 + sk);
          s0 += hv.x; s1 += hv.y;
          g0 += sigm(fr0+hu.x)*hv.x;
          g1 += sigm(fr1+hu.y)*hv.y;
        }
      }
      sh [sr][k0+sk]=s0; sh [sr][k0+sk+1]=s1;
      sgh[sr][sk]   =g0; sgh[sr][sk+1]   =g1;
    }
    __syncthreads();
    #pragma unroll
    for (int k=0;k<16;k++){
      float a1[4], a2[4];
      #pragma unroll
      for (int i=0;i<4;i++){ a1[i]=sh[tr*4+i][k0+k]; a2[i]=sgh[tr*4+i][k]; }
      #pragma unroll
      for (int j=0;j<8;j++){
        float b1 = Bz[k][tc + (j<<5)];
        float b2 = Bh[k][tc + (j<<5)];
        #pragma unroll
        for (int i=0;i<4;i++){
          acc1[i][j] = fmaf(a1[i], b1, acc1[i][j]);
          acc2[i][j] = fmaf(a2[i], b2, acc2[i][j]);
        }
      }
    }
    __syncthreads();
  }

  #pragma unroll
  for (int i=0;i<4;i++){
    int r = (tr<<2)+i; int m = bm + r;
    if (m >= M) continue;
    #pragma unroll
    for (int j=0;j<8;j++){
      int c = tc + (j<<5);
      float z   = sigm (acc1[i][j] + feat_eval(fz, m, c));
      float pre = tanhf(acc2[i][j] + feat_eval(fh, m, c));
      float v = (1.0f-z)*sh[r][c] + z*pre;
      if (m==0) v = 0.0f;
      nxt[(size_t)m*256 + c] = v;
    }
  }
}

// ---------------------------------------------------------------------------
extern "C" void kernel_launch(void* const* d_in, const int* in_sizes, int n_in,
                              void* d_out, int out_size, void* d_ws, size_t ws_size,
                              hipStream_t stream)
{
  const int* t_fnode  = (const int*)d_in[0];
  const int* t_fmess  = (const int*)d_in[1];
  const int* t_agraph = (const int*)d_in[2];
  const int* t_bgraph = (const int*)d_in[3];
  const int* t_cgraph = (const int*)d_in[4];
  const int* g_fnode  = (const int*)d_in[5];
  const int* g_fmess  = (const int*)d_in[6];
  const int* g_agraph = (const int*)d_in[7];
  const int* g_bgraph = (const int*)d_in[8];
  const int* roots    = (const int*)d_in[9];
  const float* E_c     = (const float*)d_in[10];
  const float* E_i     = (const float*)d_in[11];
  const float* Wc_w    = (const float*)d_in[12];
  const float* Wc_b    = (const float*)d_in[13];
  const float* Wi_w    = (const float*)d_in[14];
  const float* Wi_b    = (const float*)d_in[15];
  const float* Wroot_w = (const float*)d_in[16];
  const float* Wroot_b = (const float*)d_in[17];
  const float* t_Wo_w  = (const float*)d_in[18];
  const float* t_Wo_b  = (const float*)d_in[19];
  const float* t_Wz_w  = (const float*)d_in[20];
  const float* t_Wz_b  = (const float*)d_in[21];
  const float* t_Wr_w  = (const float*)d_in[22];
  const float* t_Ur_w  = (const float*)d_in[23];
  const float* t_Ur_b  = (const float*)d_in[24];
  const float* t_Wh_w  = (const float*)d_in[25];
  const float* t_Wh_b  = (const float*)d_in[26];
  const float* i_Wo_w  = (const float*)d_in[27];
  const float* i_Wo_b  = (const float*)d_in[28];
  const float* i_Wz_w  = (const float*)d_in[29];
  const float* i_Wz_b  = (const float*)d_in[30];
  const float* i_Wr_w  = (const float*)d_in[31];
  const float* i_Ur_w  = (const float*)d_in[32];
  const float* i_Ur_b  = (const float*)d_in[33];
  const float* i_Wh_w  = (const float*)d_in[34];
  const float* i_Wh_b  = (const float*)d_in[35];
  const float* g_Wo_w  = (const float*)d_in[36];
  const float* g_Wo_b  = (const float*)d_in[37];
  const float* g_Wz_w  = (const float*)d_in[38];
  const float* g_Wz_b  = (const float*)d_in[39];
  const float* g_Wr_w  = (const float*)d_in[40];
  const float* g_Ur_w  = (const float*)d_in[41];
  const float* g_Ur_b  = (const float*)d_in[42];
  const float* g_Wh_w  = (const float*)d_in[43];
  const float* g_Wh_b  = (const float*)d_in[44];

  float* out        = (float*)d_out;
  float* out_hroot  = out;
  float* out_htree  = out + (size_t)65536;
  float* out_hinter = out + (size_t)65536 + 2048000;
  float* out_hatom  = out + (size_t)65536 + 2048000 + 2048000;

  // ---- workspace: aidx first, then 3 big f32 buffers (~153.8 MB total) ----
  const size_t S = 256, MAP = 50000;
  int*   aidx = (int*)d_ws;                           // 50000 ints
  float* W0 = (float*)((char*)d_ws + 262144);
  float* W1 = W0 + MAP*S;
  float* W2 = W1 + MAP*S;

  // sub-buffers (lifetimes verified; tree GRUs only touch rows [0,16000))
  float* neibG   = W0;                      // 25000 rows (after G GRU)
  float* hatom   = W2;                      // 25000 rows (dead before I GRU)
  float* neib_t  = W0;                      // 8000 rows
  float* finb    = W0 + (size_t)8000*S;     // 8000
  float* hn_i    = W1 + (size_t)16000*S;    // 8000 (alive through I phase)
  float* hnWz    = W2 + (size_t)25000*S;    // 8000
  float* hnWr    = W2 + (size_t)33000*S;    // 8000
  float* hnWh    = W2 + (size_t)41000*S;    // 8000 (ends 49000 <= 50000)
  float* nei_i   = W0;                      // 8000
  float* hinter  = W0 + (size_t)8000*S;     // 8000
  float* finb_c  = W1 + (size_t)24000*S;    // 8000
  float* hn_t    = W1 + (size_t)32000*S;    // 8000 (alive through root)
  float* nei_t   = W0;                      // 8000
  float* hn_roots= W0 + (size_t)8000*S;     // 256
  float* nei_root= W0 + (size_t)8256*S;     // 256

  (void)in_sizes; (void)n_in; (void)out_size; (void)ws_size;

  // ---- feature descriptors -------------------------------------------------
  Feat fzg{}; fzg.otab=g_Wz_w; fzg.oidx0=aidx;      fzg.os0=1; fzg.oo0=0;
              fzg.oidx1=g_fmess+2; fzg.os1=4; fzg.oo1=40;
              fzg.oidx2=g_fmess+3; fzg.os2=4; fzg.oo2=44; fzg.bias=g_Wz_b;
  Feat frg = fzg; frg.otab=g_Wr_w; frg.bias=g_Ur_b;
  Feat fhg = fzg; fhg.otab=g_Wh_w; fhg.bias=g_Wh_b;

  Feat fzi{}; fzi.dtab=hnWz; fzi.didx=t_fmess; fzi.dstride=3;
              fzi.otab=i_Wz_w; fzi.oidx0=t_fmess+2; fzi.os0=3; fzi.oo0=256; fzi.bias=i_Wz_b;
  Feat fri = fzi; fri.dtab=hnWr; fri.otab=i_Wr_w; fri.bias=i_Ur_b;
  Feat fhi = fzi; fhi.dtab=hnWh; fhi.otab=i_Wh_w; fhi.bias=i_Wh_b;

  Feat fzt{}; fzt.dtab=hnWz; fzt.didx=t_fmess; fzt.dstride=3;
              fzt.otab=t_Wz_w; fzt.oidx0=t_fmess+2; fzt.os0=3; fzt.oo0=256; fzt.bias=t_Wz_b;
  Feat frt = fzt; frt.dtab=hnWr; frt.otab=t_Wr_w; frt.bias=t_Ur_b;
  Feat fht = fzt; fht.dtab=hnWh; fht.otab=t_Wh_w; fht.bias=t_Wh_b;

  Feat fnone{};

  // ---- GRU driver: ping W0<->W1 rows [0,M), hU = W2 rows [0,M) -------------
  auto run_gru = [&](int M, const int* bgraph, const float* Ur,
                     Feat fz, Feat fr, Feat fh,
                     const float* Wzh, const float* Whh, int depth)->float* {
    int gb = (M+63)/64;
    k_zero<<<1024,256,0,stream>>>(W0, (size_t)M*S);
    float* cur=W0; float* nxt=W1;
    for (int d=0; d<depth; ++d){
      dual_gemm<1,0><<<dim3(gb,4),256,0,stream>>>(cur, Ur, nullptr, nullptr,
                                                  W2, nullptr, M, fnone, 0);
      gru_fused<<<(M+31)/32,256,0,stream>>>(cur, W2, bgraph, Wzh, Whh,
                                            fz, fr, fh, nxt, M);
      float* t=cur; cur=nxt; nxt=t;
    }
    return cur; // depth 5 -> W1
  };

  // ==== Phase G: atom graph MPN ============================================
  k_aidx<<<(MA_+255)/256,256,0,stream>>>(g_fnode, g_fmess, aidx, MA_);
  float* hg = run_gru(MA_, g_bgraph, g_Ur_w, fzg, frg, fhg,
                      g_Wz_w + (size_t)64*256, g_Wh_w + (size_t)64*256, 5);
  k_gather_sum<<<NA_,256,0,stream>>>(hg, g_agraph, nullptr, 6, 6, neibG, NA_);
  Feat fWo{}; fWo.otab=g_Wo_w; fWo.oidx0=g_fnode; fWo.os0=1; fWo.oo0=0; fWo.bias=g_Wo_b;
  dual_gemm<1,1><<<dim3((NA_+63)/64,4),256,0,stream>>>(neibG, g_Wo_w + (size_t)40*256,
      nullptr, nullptr, hatom, out_hatom, NA_, fWo, 1);

  // ==== Phase I prep ========================================================
  k_gather_sum<<<NT_,256,0,stream>>>(hatom, t_cgraph, nullptr, 12, 12, neib_t, NT_);
  k_gather_f32<<<NT_,256,0,stream>>>(E_i, t_fnode+1, 2, finb, NT_);
  Feat fbWi{}; fbWi.bias=Wi_b;
  dual_gemm<2,1><<<dim3(NT_/64,4),256,0,stream>>>(finb, Wi_w, neib_t, Wi_w + (size_t)256*256,
      hn_i, nullptr, NT_, fbWi, 0);
  dual_gemm<1,0><<<dim3(NT_/64,4),256,0,stream>>>(hn_i, i_Wz_w, nullptr,nullptr, hnWz, nullptr, NT_, fnone, 0);
  dual_gemm<1,0><<<dim3(NT_/64,4),256,0,stream>>>(hn_i, i_Wr_w, nullptr,nullptr, hnWr, nullptr, NT_, fnone, 0);
  dual_gemm<1,0><<<dim3(NT_/64,4),256,0,stream>>>(hn_i, i_Wh_w, nullptr,nullptr, hnWh, nullptr, NT_, fnone, 0);

  // ==== Phase I GRU =========================================================
  float* hi = run_gru(MT_, t_bgraph, i_Ur_w, fzi, fri, fhi,
                      i_Wz_w + (size_t)276*256, i_Wh_w + (size_t)276*256, 5);
  k_gather_sum<<<NT_,256,0,stream>>>(hi, t_agraph, nullptr, 6, 6, nei_i, NT_);
  Feat fbWoi{}; fbWoi.bias=i_Wo_b;
  dual_gemm<2,1><<<dim3(NT_/64,4),256,0,stream>>>(hn_i, i_Wo_w, nei_i, i_Wo_w + (size_t)256*256,
      hinter, out_hinter, NT_, fbWoi, 1);

  // ==== Phase T prep ========================================================
  k_gather_f32<<<NT_,256,0,stream>>>(E_c, t_fnode+0, 2, finb_c, NT_);
  Feat fbWc{}; fbWc.bias=Wc_b;
  dual_gemm<2,1><<<dim3(NT_/64,4),256,0,stream>>>(finb_c, Wc_w, hinter, Wc_w + (size_t)256*256,
      hn_t, nullptr, NT_, fbWc, 0);
  dual_gemm<1,0><<<dim3(NT_/64,4),256,0,stream>>>(hn_t, t_Wz_w, nullptr,nullptr, hnWz, nullptr, NT_, fnone, 0);
  dual_gemm<1,0><<<dim3(NT_/64,4),256,0,stream>>>(hn_t, t_Wr_w, nullptr,nullptr, hnWr, nullptr, NT_, fnone, 0);
  dual_gemm<1,0><<<dim3(NT_/64,4),256,0,stream>>>(hn_t, t_Wh_w, nullptr,nullptr, hnWh, nullptr, NT_, fnone, 0);

  // ==== Phase T GRU =========================================================
  float* ht = run_gru(MT_, t_bgraph, t_Ur_w, fzt, frt, fht,
                      t_Wz_w + (size_t)276*256, t_Wh_w + (size_t)276*256, 5);
  k_gather_sum<<<NT_,256,0,stream>>>(ht, t_agraph, nullptr, 6, 6, nei_t, NT_);
  Feat fbWot{}; fbWot.bias=t_Wo_b;
  dual_gemm<2,1><<<dim3(NT_/64,4),256,0,stream>>>(hn_t, t_Wo_w, nei_t, t_Wo_w + (size_t)256*256,
      nullptr, out_htree, NT_, fbWot, 1);

  // ==== Root ================================================================
  k_gather_sum<<<NROOT_,256,0,stream>>>(hn_t, roots, nullptr, 1, 1, hn_roots, NROOT_);
  k_gather_sum<<<NROOT_,256,0,stream>>>(ht, t_agraph, roots, 6, 6, nei_root, NROOT_);
  Feat fbWr{}; fbWr.bias=Wroot_b;
  dual_gemm<2,2><<<dim3(NROOT_/64,4),256,0,stream>>>(hn_roots, Wroot_w, nei_root,
      Wroot_w + (size_t)256*256, nullptr, out_hroot, NROOT_, fbWr, 0);
}

// Round 4
// 4786.801 us; speedup vs baseline: 1.9356x; 1.9356x over previous
//
#include <hip/hip_runtime.h>
#include <hip/hip_bf16.h>
#include <math.h>

typedef __hip_bfloat16 bf16;

#define NT_ 8000
#define MT_ 16000
#define NA_ 25000
#define MA_ 50000
#define NROOT_ 256

// ---------------------------------------------------------------------------
struct Feat {
  const float* dtab; const int* didx; int dstride;
  const float* otab;
  const int* oidx0; int os0; int oo0;
  const int* oidx1; int os1; int oo1;
  const int* oidx2; int os2; int oo2;
  const float* bias;
};

__device__ __forceinline__ float sigm(float x){ return 1.0f/(1.0f+expf(-x)); }
__device__ __forceinline__ float ubf(unsigned int u){ union{unsigned int i; float f;} x; x.i = u<<16; return x.f; }
__device__ __forceinline__ unsigned int pack2bf(float a, float b){
  bf16 x = __float2bfloat16(a), y = __float2bfloat16(b);
  unsigned short ux = *(unsigned short*)&x, uy = *(unsigned short*)&y;
  return (unsigned int)ux | ((unsigned int)uy<<16);
}
__device__ __forceinline__ void acc4(float4& v, const float* p){
  float4 t = *(const float4*)p;
  v.x+=t.x; v.y+=t.y; v.z+=t.z; v.w+=t.w;
}
__device__ __forceinline__ float4 feat_eval4(const Feat& f, int m, int n){
  float4 v = make_float4(0,0,0,0);
  if (f.bias) acc4(v, f.bias + n);
  if (f.dtab) acc4(v, f.dtab + (size_t)f.didx[(size_t)m*f.dstride]*256 + n);
  if (f.otab){
    acc4(v, f.otab + (size_t)(f.oidx0[(size_t)m*f.os0]+f.oo0)*256 + n);
    if (f.oidx1) acc4(v, f.otab + (size_t)(f.oidx1[(size_t)m*f.os1]+f.oo1)*256 + n);
    if (f.oidx2) acc4(v, f.otab + (size_t)(f.oidx2[(size_t)m*f.os2]+f.oo2)*256 + n);
  }
  return v;
}

// ---------------------------------------------------------------------------
__global__ void k_aidx(const int* __restrict__ g_fnode, const int* __restrict__ g_fmess,
                       int* __restrict__ aidx, int M){
  int m = blockIdx.x*blockDim.x + threadIdx.x;
  if (m<M) aidx[m] = g_fnode[g_fmess[(size_t)m*4]];
}

// GRU step 1 (h0 = 0): h1 = sigmoid(fz) * tanh(fh); row 0 zeroed.
__global__ void k_step1(Feat fz, Feat fh, float* __restrict__ h1, int M){
  int idx = blockIdx.x*256 + threadIdx.x;
  int m = idx>>6, c = (idx&63)<<2;
  if (m>=M) return;
  float4 z4 = feat_eval4(fz,m,c);
  float4 p4 = feat_eval4(fh,m,c);
  float4 v;
  v.x = sigm(z4.x)*tanhf(p4.x);
  v.y = sigm(z4.y)*tanhf(p4.y);
  v.z = sigm(z4.z)*tanhf(p4.z);
  v.w = sigm(z4.w)*tanhf(p4.w);
  if (m==0) v = make_float4(0,0,0,0);
  *(float4*)(h1 + (size_t)m*256 + c) = v;
}

// dst[m] = sum_j src[idx[(rowsel?rowsel[m]:m)*istride + j]]   (wave per row, f4)
__global__ void k_gsum4(const float* __restrict__ src, const int* __restrict__ idx,
                        const int* __restrict__ rowsel, int J, int istride,
                        float* __restrict__ dst, int M){
  int wid = (blockIdx.x<<2) + (threadIdx.x>>6);
  if (wid>=M) return;
  int c = (threadIdx.x&63)<<2;
  int r = rowsel ? rowsel[wid] : wid;
  float4 s = make_float4(0,0,0,0);
  for (int j=0;j<J;j++){
    int id = idx[(size_t)r*istride+j];
    acc4(s, src + (size_t)id*256 + c);
  }
  *(float4*)(dst + (size_t)wid*256 + c) = s;
}

// Per message: sumh = sum_j h[bg[j]];  sumgh = sum_j sigmoid(fr + hU[bg[j]]) * h[bg[j]]
// hU is bf16; sumgh written bf16 (both feed saturating nonlinearities only).
__global__ __launch_bounds__(256)
void k_msg_gather(const float* __restrict__ cur, const bf16* __restrict__ hU,
                  const int* __restrict__ bgraph, Feat fr,
                  float* __restrict__ sumh, bf16* __restrict__ sumgh, int M){
  int wid = (blockIdx.x<<2) + (threadIdx.x>>6);
  if (wid>=M) return;
  int c = (threadIdx.x&63)<<2;
  float4 fr4 = feat_eval4(fr, wid, c);
  const int* bg = bgraph + (size_t)wid*6;
  float4 s = make_float4(0,0,0,0);
  float4 g = make_float4(0,0,0,0);
  #pragma unroll
  for (int j=0;j<6;j++){
    int id = bg[j];
    float4 h4 = *(const float4*)(cur + (size_t)id*256 + c);
    uint2  u2 = *(const uint2*)(hU  + (size_t)id*256 + c);
    float u0=ubf(u2.x&0xffffu), u1=ubf(u2.x>>16), u2f=ubf(u2.y&0xffffu), u3=ubf(u2.y>>16);
    s.x+=h4.x; s.y+=h4.y; s.z+=h4.z; s.w+=h4.w;
    g.x += sigm(fr4.x+u0 )*h4.x;
    g.y += sigm(fr4.y+u1 )*h4.y;
    g.z += sigm(fr4.z+u2f)*h4.z;
    g.w += sigm(fr4.w+u3 )*h4.w;
  }
  *(float4*)(sumh + (size_t)wid*256 + c) = s;
  uint2 p; p.x = pack2bf(g.x,g.y); p.y = pack2bf(g.z,g.w);
  *(uint2*)(sumgh + (size_t)wid*256 + c) = p;
}

// ---------------------------------------------------------------------------
// gemm256: C = epilogue(A1@B1 [+ A2@B2]).  K=256, N=256 (full width, grid.x only).
// BM=32, 256 threads, 4x8 micro-tile. A f32 (A2 optionally bf16), B f32.
// MODE 0: C = A1@B1                      MODE 1: relu(sum + feat f1), mask0
// MODE 2: tanh(sum + feat f1)
// MODE 3: z=sig(P1+f1); pre=tanh(P2+f2); C=(1-z)*A1 + z*pre; row0=0
//         (Cf may alias A1: each block reads only its own rows; all global A
//          reads complete before the final barrier, epilogue writes after.)
// ---------------------------------------------------------------------------
template<int NG, int MODE, int A2BF>
__global__ __launch_bounds__(256)
void gemm256(const float* __restrict__ A1, const float* __restrict__ B1,
             const void* __restrict__ A2v, const float* __restrict__ B2,
             float* __restrict__ Cf, float* __restrict__ Cf2,
             bf16* __restrict__ Cb, int M,
             Feat f1, Feat f2, int mask0)
{
  __shared__ float As[NG][16][36];
  __shared__ float Bs[NG][16][260];
  const int tid = threadIdx.x;
  const int bm = blockIdx.x<<5;
  const int tm = (tid>>5)<<2;      // 0..28
  const int c0 = (tid&31)<<2;      // 0..124 (+128 for second half)

  float acc[NG][4][8];
  #pragma unroll
  for (int g=0;g<NG;g++)
    #pragma unroll
    for (int i=0;i<4;i++)
      #pragma unroll
      for (int j=0;j<8;j++) acc[g][i][j]=0.f;

  const int t7  = tid & 127;
  const int alm = t7>>2;           // 0..31
  const int alk = (t7&3)<<2;       // 0,4,8,12
  const int arow = bm + alm;
  const int amat = (NG==2)? (tid>>7) : 0;
  const bool astage = (NG==2) || (tid<128);
  const bf16*  A2b = (const bf16*)A2v;
  const float* A2f = (const float*)A2v;

  for (int k0=0;k0<256;k0+=16){
    float a0=0,a1=0,a2=0,a3=0;
    if (astage && arow<M){
      if (A2BF && amat==1){
        uint2 u = *(const uint2*)(A2b + (size_t)arow*256 + k0 + alk);
        a0=ubf(u.x&0xffffu); a1=ubf(u.x>>16); a2=ubf(u.y&0xffffu); a3=ubf(u.y>>16);
      } else {
        const float* src = (amat==0)? A1 : A2f;
        float4 v = *(const float4*)(src + (size_t)arow*256 + k0 + alk);
        a0=v.x; a1=v.y; a2=v.z; a3=v.w;
      }
    }
    float4 breg[NG][4];
    #pragma unroll
    for (int g=0; g<NG; g++){
      const float* B = (g==0)? B1 : B2;
      #pragma unroll
      for (int j=0;j<4;j++){
        int slot = tid + 256*j;
        int kb = slot>>6, nb = (slot&63)<<2;
        breg[g][j] = *(const float4*)(B + (size_t)(k0+kb)*256 + nb);
      }
    }
    __syncthreads();
    if (astage){
      As[amat][alk+0][alm]=a0; As[amat][alk+1][alm]=a1;
      As[amat][alk+2][alm]=a2; As[amat][alk+3][alm]=a3;
    }
    #pragma unroll
    for (int g=0; g<NG; g++){
      #pragma unroll
      for (int j=0;j<4;j++){
        int slot = tid + 256*j;
        int kb = slot>>6, nb = (slot&63)<<2;
        *(float4*)&Bs[g][kb][nb] = breg[g][j];
      }
    }
    __syncthreads();
    #pragma unroll
    for (int k=0;k<16;k++){
      #pragma unroll
      for (int g=0;g<NG;g++){
        float4 av = *(const float4*)&As[g][k][tm];
        float4 b0 = *(const float4*)&Bs[g][k][c0];
        float4 b1 = *(const float4*)&Bs[g][k][c0+128];
        float a_[4]={av.x,av.y,av.z,av.w};
        float b_[8]={b0.x,b0.y,b0.z,b0.w,b1.x,b1.y,b1.z,b1.w};
        #pragma unroll
        for (int i=0;i<4;i++)
          #pragma unroll
          for (int j=0;j<8;j++)
            acc[g][i][j] = fmaf(a_[i], b_[j], acc[g][i][j]);
      }
    }
  }

  #pragma unroll
  for (int i=0;i<4;i++){
    int m = bm + tm + i;
    if (m >= M) continue;
    #pragma unroll
    for (int half=0; half<2; half++){
      int c = c0 + half*128;
      float4 r;
      float* rr = &r.x;
      if (MODE==3){
        float4 fz4 = feat_eval4(f1, m, c);
        float4 fh4 = feat_eval4(f2, m, c);
        float4 s4  = *(const float4*)(A1 + (size_t)m*256 + c);
        float fzv[4]={fz4.x,fz4.y,fz4.z,fz4.w};
        float fhv[4]={fh4.x,fh4.y,fh4.z,fh4.w};
        float sv[4] ={s4.x,s4.y,s4.z,s4.w};
        #pragma unroll
        for (int j=0;j<4;j++){
          float z   = sigm (acc[0][i][half*4+j] + fzv[j]);
          float pre = tanhf(acc[1][i][half*4+j] + fhv[j]);
          rr[j] = (m==0) ? 0.f : ((1.f-z)*sv[j] + z*pre);
        }
      } else if (MODE==0){
        #pragma unroll
        for (int j=0;j<4;j++) rr[j] = acc[0][i][half*4+j];
      } else {
        float4 ft = feat_eval4(f1, m, c);
        float fv[4]={ft.x,ft.y,ft.z,ft.w};
        #pragma unroll
        for (int j=0;j<4;j++){
          float s = acc[0][i][half*4+j] + (NG>1?acc[1][i][half*4+j]:0.f) + fv[j];
          float v = (MODE==1)? fmaxf(s,0.f) : tanhf(s);
          if (MODE==1 && mask0 && m==0) v = 0.f;
          rr[j] = v;
        }
      }
      if (Cf)  *(float4*)(Cf  + (size_t)m*256+c) = r;
      if (Cf2) *(float4*)(Cf2 + (size_t)m*256+c) = r;
      if (Cb){
        uint2 p; p.x = pack2bf(r.x,r.y); p.y = pack2bf(r.z,r.w);
        *(uint2*)(Cb + (size_t)m*256+c) = p;
      }
    }
  }
}

// ---------------------------------------------------------------------------
extern "C" void kernel_launch(void* const* d_in, const int* in_sizes, int n_in,
                              void* d_out, int out_size, void* d_ws, size_t ws_size,
                              hipStream_t stream)
{
  const int* t_fnode  = (const int*)d_in[0];
  const int* t_fmess  = (const int*)d_in[1];
  const int* t_agraph = (const int*)d_in[2];
  const int* t_bgraph = (const int*)d_in[3];
  const int* t_cgraph = (const int*)d_in[4];
  const int* g_fnode  = (const int*)d_in[5];
  const int* g_fmess  = (const int*)d_in[6];
  const int* g_agraph = (const int*)d_in[7];
  const int* g_bgraph = (const int*)d_in[8];
  const int* roots    = (const int*)d_in[9];
  const float* E_c     = (const float*)d_in[10];
  const float* E_i     = (const float*)d_in[11];
  const float* Wc_w    = (const float*)d_in[12];
  const float* Wc_b    = (const float*)d_in[13];
  const float* Wi_w    = (const float*)d_in[14];
  const float* Wi_b    = (const float*)d_in[15];
  const float* Wroot_w = (const float*)d_in[16];
  const float* Wroot_b = (const float*)d_in[17];
  const float* t_Wo_w  = (const float*)d_in[18];
  const float* t_Wo_b  = (const float*)d_in[19];
  const float* t_Wz_w  = (const float*)d_in[20];
  const float* t_Wz_b  = (const float*)d_in[21];
  const float* t_Wr_w  = (const float*)d_in[22];
  const float* t_Ur_w  = (const float*)d_in[23];
  const float* t_Ur_b  = (const float*)d_in[24];
  const float* t_Wh_w  = (const float*)d_in[25];
  const float* t_Wh_b  = (const float*)d_in[26];
  const float* i_Wo_w  = (const float*)d_in[27];
  const float* i_Wo_b  = (const float*)d_in[28];
  const float* i_Wz_w  = (const float*)d_in[29];
  const float* i_Wz_b  = (const float*)d_in[30];
  const float* i_Wr_w  = (const float*)d_in[31];
  const float* i_Ur_w  = (const float*)d_in[32];
  const float* i_Ur_b  = (const float*)d_in[33];
  const float* i_Wh_w  = (const float*)d_in[34];
  const float* i_Wh_b  = (const float*)d_in[35];
  const float* g_Wo_w  = (const float*)d_in[36];
  const float* g_Wo_b  = (const float*)d_in[37];
  const float* g_Wz_w  = (const float*)d_in[38];
  const float* g_Wz_b  = (const float*)d_in[39];
  const float* g_Wr_w  = (const float*)d_in[40];
  const float* g_Ur_w  = (const float*)d_in[41];
  const float* g_Ur_b  = (const float*)d_in[42];
  const float* g_Wh_w  = (const float*)d_in[43];
  const float* g_Wh_b  = (const float*)d_in[44];

  float* out        = (float*)d_out;
  float* out_hroot  = out;
  float* out_htree  = out + (size_t)65536;
  float* out_hinter = out + (size_t)65536 + 2048000;
  float* out_hatom  = out + (size_t)65536 + 2048000 + 2048000;

  // ---- workspace (153.86 MB total, same footprint as the passing round) ---
  const size_t S = 256, MAP = 50000;
  int*   aidx = (int*)d_ws;                          // 50000 ints
  float* Wa   = (float*)((char*)d_ws + 262144);      // 50000x256 f32
  float* Wb   = Wa + MAP*S;                          // 50000x256 f32
  bf16*  Wc16 = (bf16*)(Wb + MAP*S);                 // 50000x256 bf16 (sumgh)
  bf16*  Wh16 = Wc16 + MAP*S;                        // 50000x256 bf16 (hU)

  // tree-phase sub-buffers in Wa rows >=16000 / Wb (lifetimes traced in notes)
  float* neibG    = Wb;                       // 25000 rows
  float* hatom    = Wb + (size_t)25000*S;     // 25000 rows
  float* neib_t   = Wa;                       // 8000
  float* finb     = Wa + (size_t)8000*S;      // 8000
  float* hn_i     = Wa + (size_t)16000*S;     // 8000 (alive through I phase)
  float* hnWz     = Wa + (size_t)24000*S;     // 8000
  float* hnWr     = Wa + (size_t)32000*S;     // 8000
  float* hnWh     = Wa + (size_t)40000*S;     // 8000 (ends 48000 <= 50000)
  float* nei_i    = Wb;                       // 8000
  float* hinter   = Wb + (size_t)8000*S;      // 8000
  float* finb_c   = Wa;                       // 8000
  float* hn_t     = Wa + (size_t)16000*S;     // 8000 (overwrites dead hn_i)
  float* nei_t    = Wb;                       // 8000
  float* hn_roots = Wb + (size_t)8000*S;      // 256
  float* nei_root = Wb + (size_t)8256*S;      // 256

  (void)in_sizes; (void)n_in; (void)out_size; (void)ws_size;

  // ---- feature descriptors -------------------------------------------------
  Feat fzg{}; fzg.otab=g_Wz_w; fzg.oidx0=aidx;      fzg.os0=1; fzg.oo0=0;
              fzg.oidx1=g_fmess+2; fzg.os1=4; fzg.oo1=40;
              fzg.oidx2=g_fmess+3; fzg.os2=4; fzg.oo2=44; fzg.bias=g_Wz_b;
  Feat frg = fzg; frg.otab=g_Wr_w; frg.bias=g_Ur_b;
  Feat fhg = fzg; fhg.otab=g_Wh_w; fhg.bias=g_Wh_b;

  Feat fzi{}; fzi.dtab=hnWz; fzi.didx=t_fmess; fzi.dstride=3;
              fzi.otab=i_Wz_w; fzi.oidx0=t_fmess+2; fzi.os0=3; fzi.oo0=256; fzi.bias=i_Wz_b;
  Feat fri = fzi; fri.dtab=hnWr; fri.otab=i_Wr_w; fri.bias=i_Ur_b;
  Feat fhi = fzi; fhi.dtab=hnWh; fhi.otab=i_Wh_w; fhi.bias=i_Wh_b;

  Feat fzt = fzi; fzt.otab=t_Wz_w; fzt.bias=t_Wz_b;
  Feat frt = fri; frt.otab=t_Wr_w; frt.bias=t_Ur_b;
  Feat fht = fhi; fht.otab=t_Wh_w; fht.bias=t_Wh_b;

  Feat fnone{};

  // ---- GRU driver: step1 elementwise, then 4 x (hU, gather, GRU-gemm) ------
  auto run_gru = [&](int M, const int* bgraph, const float* Ur,
                     Feat fz, Feat fr, Feat fh,
                     const float* Wzh, const float* Whh)->float* {
    int gb32 = (M+31)/32, gb4 = (M+3)/4;
    k_step1<<<gb4*16,256,0,stream>>>(fz, fh, Wa, M);      // gb4*16 == M*64/256 blocks
    float* cur=Wa; float* nxt=Wb;
    for (int d=0; d<4; ++d){
      gemm256<1,0,0><<<gb32,256,0,stream>>>(cur, Ur, nullptr, nullptr,
                                            nullptr, nullptr, Wh16, M, fnone, fnone, 0);
      k_msg_gather<<<gb4,256,0,stream>>>(cur, Wh16, bgraph, fr, nxt, Wc16, M);
      gemm256<2,3,1><<<gb32,256,0,stream>>>(nxt, Wzh, Wc16, Whh,
                                            nxt, nullptr, nullptr, M, fz, fh, 0);
      float* t=cur; cur=nxt; nxt=t;
    }
    return cur; // 4 swaps -> Wa
  };

  // ==== Phase G: atom graph MPN ============================================
  k_aidx<<<(MA_+255)/256,256,0,stream>>>(g_fnode, g_fmess, aidx, MA_);
  float* hg = run_gru(MA_, g_bgraph, g_Ur_w, fzg, frg, fhg,
                      g_Wz_w + (size_t)64*256, g_Wh_w + (size_t)64*256);
  k_gsum4<<<(NA_+3)/4,256,0,stream>>>(hg, g_agraph, nullptr, 6, 6, neibG, NA_);
  Feat fWo{}; fWo.otab=g_Wo_w; fWo.oidx0=g_fnode; fWo.os0=1; fWo.oo0=0; fWo.bias=g_Wo_b;
  gemm256<1,1,0><<<(NA_+31)/32,256,0,stream>>>(neibG, g_Wo_w + (size_t)40*256,
      nullptr, nullptr, hatom, out_hatom, nullptr, NA_, fWo, fnone, 1);

  // ==== Phase I prep ========================================================
  k_gsum4<<<(NT_+3)/4,256,0,stream>>>(hatom, t_cgraph, nullptr, 12, 12, neib_t, NT_);
  k_gsum4<<<(NT_+3)/4,256,0,stream>>>(E_i, t_fnode+1, nullptr, 1, 2, finb, NT_);
  Feat fbWi{}; fbWi.bias=Wi_b;
  gemm256<2,1,0><<<NT_/32,256,0,stream>>>(finb, Wi_w, neib_t, Wi_w + (size_t)256*256,
      hn_i, nullptr, nullptr, NT_, fbWi, fnone, 0);
  gemm256<1,0,0><<<NT_/32,256,0,stream>>>(hn_i, i_Wz_w, nullptr,nullptr, hnWz, nullptr, nullptr, NT_, fnone, fnone, 0);
  gemm256<1,0,0><<<NT_/32,256,0,stream>>>(hn_i, i_Wr_w, nullptr,nullptr, hnWr, nullptr, nullptr, NT_, fnone, fnone, 0);
  gemm256<1,0,0><<<NT_/32,256,0,stream>>>(hn_i, i_Wh_w, nullptr,nullptr, hnWh, nullptr, nullptr, NT_, fnone, fnone, 0);

  // ==== Phase I GRU =========================================================
  float* hi = run_gru(MT_, t_bgraph, i_Ur_w, fzi, fri, fhi,
                      i_Wz_w + (size_t)276*256, i_Wh_w + (size_t)276*256);
  k_gsum4<<<(NT_+3)/4,256,0,stream>>>(hi, t_agraph, nullptr, 6, 6, nei_i, NT_);
  Feat fbWoi{}; fbWoi.bias=i_Wo_b;
  gemm256<2,1,0><<<NT_/32,256,0,stream>>>(hn_i, i_Wo_w, nei_i, i_Wo_w + (size_t)256*256,
      hinter, out_hinter, nullptr, NT_, fbWoi, fnone, 1);

  // ==== Phase T prep ========================================================
  k_gsum4<<<(NT_+3)/4,256,0,stream>>>(E_c, t_fnode+0, nullptr, 1, 2, finb_c, NT_);
  Feat fbWc{}; fbWc.bias=Wc_b;
  gemm256<2,1,0><<<NT_/32,256,0,stream>>>(finb_c, Wc_w, hinter, Wc_w + (size_t)256*256,
      hn_t, nullptr, nullptr, NT_, fbWc, fnone, 0);
  gemm256<1,0,0><<<NT_/32,256,0,stream>>>(hn_t, t_Wz_w, nullptr,nullptr, hnWz, nullptr, nullptr, NT_, fnone, fnone, 0);
  gemm256<1,0,0><<<NT_/32,256,0,stream>>>(hn_t, t_Wr_w, nullptr,nullptr, hnWr, nullptr, nullptr, NT_, fnone, fnone, 0);
  gemm256<1,0,0><<<NT_/32,256,0,stream>>>(hn_t, t_Wh_w, nullptr,nullptr, hnWh, nullptr, nullptr, NT_, fnone, fnone, 0);

  // ==== Phase T GRU =========================================================
  float* ht = run_gru(MT_, t_bgraph, t_Ur_w, fzt, frt, fht,
                      t_Wz_w + (size_t)276*256, t_Wh_w + (size_t)276*256);
  k_gsum4<<<(NT_+3)/4,256,0,stream>>>(ht, t_agraph, nullptr, 6, 6, nei_t, NT_);
  Feat fbWot{}; fbWot.bias=t_Wo_b;
  gemm256<2,1,0><<<NT_/32,256,0,stream>>>(hn_t, t_Wo_w, nei_t, t_Wo_w + (size_t)256*256,
      out_htree, nullptr, nullptr, NT_, fbWot, fnone, 1);

  // ==== Root ================================================================
  k_gsum4<<<(NROOT_+3)/4,256,0,stream>>>(hn_t, roots, nullptr, 1, 1, hn_roots, NROOT_);
  k_gsum4<<<(NROOT_+3)/4,256,0,stream>>>(ht, t_agraph, roots, 6, 6, nei_root, NROOT_);
  Feat fbWr{}; fbWr.bias=Wroot_b;
  gemm256<2,2,0><<<NROOT_/32,256,0,stream>>>(hn_roots, Wroot_w, nei_root,
      Wroot_w + (size_t)256*256, out_hroot, nullptr, nullptr, NROOT_, fbWr, fnone, 0);
}

// Round 5
// 3710.062 us; speedup vs baseline: 2.4974x; 1.2902x over previous
//
#include <hip/hip_runtime.h>
#include <hip/hip_bf16.h>
#include <math.h>

typedef __hip_bfloat16 bf16;
typedef __attribute__((ext_vector_type(8))) short  bf16x8;
typedef __attribute__((ext_vector_type(4))) float  f32x4;

#define NT_ 8000
#define MT_ 16000
#define NA_ 25000
#define MA_ 50000
#define NROOT_ 256

// ---------------------------------------------------------------------------
struct Feat {
  const float* dtab; const int* didx; int dstride;
  const float* otab;
  const int* oidx0; int os0; int oo0;
  const int* oidx1; int os1; int oo1;
  const int* oidx2; int os2; int oo2;
  const float* bias;
};

__device__ __forceinline__ float sigm(float x){ return 1.0f/(1.0f+expf(-x)); }
__device__ __forceinline__ float ubf(unsigned int u){ union{unsigned int i; float f;} x; x.i = u<<16; return x.f; }
__device__ __forceinline__ unsigned int pack2bf(float a, float b){
  bf16 x = __float2bfloat16(a), y = __float2bfloat16(b);
  unsigned short ux = *(unsigned short*)&x, uy = *(unsigned short*)&y;
  return (unsigned int)ux | ((unsigned int)uy<<16);
}
__device__ __forceinline__ short f2bf_s(float f){
  bf16 b = __float2bfloat16(f);
  return *(short*)&b;
}
__device__ __forceinline__ float bfs2f(short s){ return ubf((unsigned short)s); }

__device__ __forceinline__ void acc4(float4& v, const float* p){
  float4 t = *(const float4*)p;
  v.x+=t.x; v.y+=t.y; v.z+=t.z; v.w+=t.w;
}
__device__ __forceinline__ float4 feat_eval4(const Feat& f, int m, int n){
  float4 v = make_float4(0,0,0,0);
  if (f.bias) acc4(v, f.bias + n);
  if (f.dtab) acc4(v, f.dtab + (size_t)f.didx[(size_t)m*f.dstride]*256 + n);
  if (f.otab){
    acc4(v, f.otab + (size_t)(f.oidx0[(size_t)m*f.os0]+f.oo0)*256 + n);
    if (f.oidx1) acc4(v, f.otab + (size_t)(f.oidx1[(size_t)m*f.os1]+f.oo1)*256 + n);
    if (f.oidx2) acc4(v, f.otab + (size_t)(f.oidx2[(size_t)m*f.os2]+f.oo2)*256 + n);
  }
  return v;
}
__device__ __forceinline__ float feat_eval(const Feat& f, int m, int n){
  float v = 0.0f;
  if (f.bias) v += f.bias[n];
  if (f.dtab) v += f.dtab[(size_t)f.didx[(size_t)m*f.dstride]*256 + n];
  if (f.otab){
    v += f.otab[((size_t)(f.oidx0[(size_t)m*f.os0]+f.oo0))*256 + n];
    if (f.oidx1) v += f.otab[((size_t)(f.oidx1[(size_t)m*f.os1]+f.oo1))*256 + n];
    if (f.oidx2) v += f.otab[((size_t)(f.oidx2[(size_t)m*f.os2]+f.oo2))*256 + n];
  }
  return v;
}

// ---------------------------------------------------------------------------
__global__ void k_aidx(const int* __restrict__ g_fnode, const int* __restrict__ g_fmess,
                       int* __restrict__ aidx, int M){
  int m = blockIdx.x*blockDim.x + threadIdx.x;
  if (m<M) aidx[m] = g_fnode[g_fmess[(size_t)m*4]];
}

// Split a 256x256 f32 weight (row-major W[k][n]) into MFMA-fragment-swizzled
// bf16 hi/lo planes: element (k,n) -> ((k>>5)*16 + (n>>4))*512 + lane*8 + j,
// lane=(n&15)+16*((k>>3)&3), j=k&7.
__global__ void k_splitw(const float* __restrict__ W, short* __restrict__ hi,
                         short* __restrict__ lo){
  int idx = blockIdx.x*256 + threadIdx.x;   // 65536
  int k = idx>>8, n = idx&255;
  float w = W[idx];
  int dest = (((k>>5)*16 + (n>>4))<<9) + (((n&15) + (((k>>3)&3)<<4))<<3) + (k&7);
  short h = f2bf_s(w);
  hi[dest]=h;
  lo[dest]=f2bf_s(w - bfs2f(h));
}

// GRU step 1 (h0 = 0): h1 = sigmoid(fz) * tanh(fh); row 0 zeroed.
__global__ void k_step1(Feat fz, Feat fh, float* __restrict__ h1, int M){
  int idx = blockIdx.x*256 + threadIdx.x;
  int m = idx>>6, c = (idx&63)<<2;
  if (m>=M) return;
  float4 z4 = feat_eval4(fz,m,c);
  float4 p4 = feat_eval4(fh,m,c);
  float4 v;
  v.x = sigm(z4.x)*tanhf(p4.x);
  v.y = sigm(z4.y)*tanhf(p4.y);
  v.z = sigm(z4.z)*tanhf(p4.z);
  v.w = sigm(z4.w)*tanhf(p4.w);
  if (m==0) v = make_float4(0,0,0,0);
  *(float4*)(h1 + (size_t)m*256 + c) = v;
}

// dst[m] = sum_j src[idx[(rowsel?rowsel[m]:m)*istride + j]]   (wave per row)
__global__ void k_gsum4(const float* __restrict__ src, const int* __restrict__ idx,
                        const int* __restrict__ rowsel, int J, int istride,
                        float* __restrict__ dst, int M){
  int wid = (blockIdx.x<<2) + (threadIdx.x>>6);
  if (wid>=M) return;
  int c = (threadIdx.x&63)<<2;
  int r = rowsel ? rowsel[wid] : wid;
  float4 s = make_float4(0,0,0,0);
  for (int j=0;j<J;j++){
    int id = idx[(size_t)r*istride+j];
    acc4(s, src + (size_t)id*256 + c);
  }
  *(float4*)(dst + (size_t)wid*256 + c) = s;
}

// Per message: sumh = sum_j h[bg[j]];  sumgh = sum_j sigmoid(fr + hU[bg[j]]) * h[bg[j]]
__global__ __launch_bounds__(256)
void k_msg_gather(const float* __restrict__ cur, const bf16* __restrict__ hU,
                  const int* __restrict__ bgraph, Feat fr,
                  float* __restrict__ sumh, bf16* __restrict__ sumgh, int M){
  int wid = (blockIdx.x<<2) + (threadIdx.x>>6);
  if (wid>=M) return;
  int c = (threadIdx.x&63)<<2;
  float4 fr4 = feat_eval4(fr, wid, c);
  const int* bg = bgraph + (size_t)wid*6;
  float4 s = make_float4(0,0,0,0);
  float4 g = make_float4(0,0,0,0);
  #pragma unroll
  for (int j=0;j<6;j++){
    int id = bg[j];
    float4 h4 = *(const float4*)(cur + (size_t)id*256 + c);
    uint2  u2 = *(const uint2*)(hU  + (size_t)id*256 + c);
    float u0=ubf(u2.x&0xffffu), u1=ubf(u2.x>>16), u2f=ubf(u2.y&0xffffu), u3=ubf(u2.y>>16);
    s.x+=h4.x; s.y+=h4.y; s.z+=h4.z; s.w+=h4.w;
    g.x += sigm(fr4.x+u0 )*h4.x;
    g.y += sigm(fr4.y+u1 )*h4.y;
    g.z += sigm(fr4.z+u2f)*h4.z;
    g.w += sigm(fr4.w+u3 )*h4.w;
  }
  *(float4*)(sumh + (size_t)wid*256 + c) = s;
  uint2 p; p.x = pack2bf(g.x,g.y); p.y = pack2bf(g.z,g.w);
  *(uint2*)(sumgh + (size_t)wid*256 + c) = p;
}

// ---------------------------------------------------------------------------
// MFMA building blocks. Block = 256 thr = 4 waves; wave (wr=wave>>1, wc=wave&1)
// owns rows [bid*32 + wr*16, +16) x cols [wc*128, +128).  K=256 in 8 chunks.
// ---------------------------------------------------------------------------
__device__ __forceinline__ void build_a(const float* p, bf16x8& hi, bf16x8& lo){
  float4 v0 = *(const float4*)p;
  float4 v1 = *(const float4*)(p+4);
  float vv[8]={v0.x,v0.y,v0.z,v0.w,v1.x,v1.y,v1.z,v1.w};
  #pragma unroll
  for (int j=0;j<8;j++){
    short h = f2bf_s(vv[j]);
    hi[j]=h;
    lo[j]=f2bf_s(vv[j]-bfs2f(h));
  }
}

// hU = bf16( h @ Ur ),  bf16x3 precision, row-major bf16 output.
__global__ __launch_bounds__(256)
void mfma_hU(const float* __restrict__ hin, const short* __restrict__ Bh,
             const short* __restrict__ Bl, bf16* __restrict__ hU, int M)
{
  const int tid=threadIdx.x, lane=tid&63, wave=tid>>6;
  const int wr=wave>>1, wc=wave&1;
  const int rbase = (blockIdx.x<<5) + (wr<<4);
  const int row_a = rbase + (lane&15);
  const int koff  = (lane>>4)<<3;
  const bool av = row_a < M;
  f32x4 zero = {0.f,0.f,0.f,0.f};
  f32x4 acc[8];
  #pragma unroll
  for (int t=0;t<8;t++) acc[t]=zero;

  for (int kc=0;kc<8;kc++){
    bf16x8 ah={0,0,0,0,0,0,0,0}, al={0,0,0,0,0,0,0,0};
    if (av) build_a(hin + (size_t)row_a*256 + kc*32 + koff, ah, al);
    #pragma unroll
    for (int t=0;t<8;t++){
      int off = (((kc<<4) + (wc<<3) + t)<<9) + (lane<<3);
      bf16x8 bh = *(const bf16x8*)(Bh+off);
      bf16x8 bl = *(const bf16x8*)(Bl+off);
      acc[t]=__builtin_amdgcn_mfma_f32_16x16x32_bf16(ah,bh,acc[t],0,0,0);
      acc[t]=__builtin_amdgcn_mfma_f32_16x16x32_bf16(al,bh,acc[t],0,0,0);
      acc[t]=__builtin_amdgcn_mfma_f32_16x16x32_bf16(ah,bl,acc[t],0,0,0);
    }
  }
  const int rr = rbase + ((lane>>4)<<2);
  const int cl = lane&15;
  #pragma unroll
  for (int t=0;t<8;t++){
    int col = (((wc<<3)+t)<<4) + cl;
    #pragma unroll
    for (int r=0;r<4;r++){
      int m = rr + r;
      if (m < M) hU[(size_t)m*256+col] = __float2bfloat16(acc[t][r]);
    }
  }
}

// GRU step: z = sig(sumh@Wzh + fz); pre = tanh(sumgh@Whh + fh);
// h = (1-z)*sumh + z*pre; row0=0.  z-path bf16x3; h-path sumgh(bf16) x split-B.
__global__ __launch_bounds__(256)
void mfma_gru(const float* __restrict__ sumh, const bf16* __restrict__ sumgh,
              const short* __restrict__ Bzh, const short* __restrict__ Bzl,
              const short* __restrict__ Bhh, const short* __restrict__ Bhl,
              Feat fz, Feat fh, float* __restrict__ hout, int M)
{
  const int tid=threadIdx.x, lane=tid&63, wave=tid>>6;
  const int wr=wave>>1, wc=wave&1;
  const int rbase = (blockIdx.x<<5) + (wr<<4);
  const int row_a = rbase + (lane&15);
  const int koff  = (lane>>4)<<3;
  const bool av = row_a < M;
  f32x4 zero = {0.f,0.f,0.f,0.f};
  f32x4 accz[8], acch[8];
  #pragma unroll
  for (int t=0;t<8;t++){ accz[t]=zero; acch[t]=zero; }

  for (int kc=0;kc<8;kc++){
    bf16x8 a1h={0,0,0,0,0,0,0,0}, a1l={0,0,0,0,0,0,0,0}, a2={0,0,0,0,0,0,0,0};
    if (av){
      build_a(sumh + (size_t)row_a*256 + kc*32 + koff, a1h, a1l);
      a2 = *(const bf16x8*)(const void*)(sumgh + (size_t)row_a*256 + kc*32 + koff);
    }
    #pragma unroll
    for (int t=0;t<8;t++){
      int off = (((kc<<4) + (wc<<3) + t)<<9) + (lane<<3);
      bf16x8 bzh = *(const bf16x8*)(Bzh+off);
      bf16x8 bzl = *(const bf16x8*)(Bzl+off);
      bf16x8 bhh = *(const bf16x8*)(Bhh+off);
      bf16x8 bhl = *(const bf16x8*)(Bhl+off);
      accz[t]=__builtin_amdgcn_mfma_f32_16x16x32_bf16(a1h,bzh,accz[t],0,0,0);
      accz[t]=__builtin_amdgcn_mfma_f32_16x16x32_bf16(a1l,bzh,accz[t],0,0,0);
      accz[t]=__builtin_amdgcn_mfma_f32_16x16x32_bf16(a1h,bzl,accz[t],0,0,0);
      acch[t]=__builtin_amdgcn_mfma_f32_16x16x32_bf16(a2 ,bhh,acch[t],0,0,0);
      acch[t]=__builtin_amdgcn_mfma_f32_16x16x32_bf16(a2 ,bhl,acch[t],0,0,0);
    }
  }
  const int rr = rbase + ((lane>>4)<<2);
  const int cl = lane&15;
  #pragma unroll
  for (int t=0;t<8;t++){
    int col = (((wc<<3)+t)<<4) + cl;
    #pragma unroll
    for (int r=0;r<4;r++){
      int m = rr + r;
      if (m>=M) continue;
      float z   = sigm (accz[t][r] + feat_eval(fz,m,col));
      float pre = tanhf(acch[t][r] + feat_eval(fh,m,col));
      float sh  = sumh[(size_t)m*256+col];
      float v = (m==0) ? 0.f : ((1.f-z)*sh + z*pre);
      hout[(size_t)m*256+col] = v;
    }
  }
}

// ---------------------------------------------------------------------------
// Vector GEMM for the non-GRU projections (proven in round 4, unchanged).
// ---------------------------------------------------------------------------
template<int NG, int MODE, int A2BF>
__global__ __launch_bounds__(256)
void gemm256(const float* __restrict__ A1, const float* __restrict__ B1,
             const void* __restrict__ A2v, const float* __restrict__ B2,
             float* __restrict__ Cf, float* __restrict__ Cf2,
             bf16* __restrict__ Cb, int M,
             Feat f1, Feat f2, int mask0)
{
  __shared__ float As[NG][16][36];
  __shared__ float Bs[NG][16][260];
  const int tid = threadIdx.x;
  const int bm = blockIdx.x<<5;
  const int tm = (tid>>5)<<2;
  const int c0 = (tid&31)<<2;

  float acc[NG][4][8];
  #pragma unroll
  for (int g=0;g<NG;g++)
    #pragma unroll
    for (int i=0;i<4;i++)
      #pragma unroll
      for (int j=0;j<8;j++) acc[g][i][j]=0.f;

  const int t7  = tid & 127;
  const int alm = t7>>2;
  const int alk = (t7&3)<<2;
  const int arow = bm + alm;
  const int amat = (NG==2)? (tid>>7) : 0;
  const bool astage = (NG==2) || (tid<128);
  const bf16*  A2b = (const bf16*)A2v;
  const float* A2f = (const float*)A2v;

  for (int k0=0;k0<256;k0+=16){
    float a0=0,a1=0,a2=0,a3=0;
    if (astage && arow<M){
      if (A2BF && amat==1){
        uint2 u = *(const uint2*)(A2b + (size_t)arow*256 + k0 + alk);
        a0=ubf(u.x&0xffffu); a1=ubf(u.x>>16); a2=ubf(u.y&0xffffu); a3=ubf(u.y>>16);
      } else {
        const float* src = (amat==0)? A1 : A2f;
        float4 v = *(const float4*)(src + (size_t)arow*256 + k0 + alk);
        a0=v.x; a1=v.y; a2=v.z; a3=v.w;
      }
    }
    float4 breg[NG][4];
    #pragma unroll
    for (int g=0; g<NG; g++){
      const float* B = (g==0)? B1 : B2;
      #pragma unroll
      for (int j=0;j<4;j++){
        int slot = tid + 256*j;
        int kb = slot>>6, nb = (slot&63)<<2;
        breg[g][j] = *(const float4*)(B + (size_t)(k0+kb)*256 + nb);
      }
    }
    __syncthreads();
    if (astage){
      As[amat][alk+0][alm]=a0; As[amat][alk+1][alm]=a1;
      As[amat][alk+2][alm]=a2; As[amat][alk+3][alm]=a3;
    }
    #pragma unroll
    for (int g=0; g<NG; g++){
      #pragma unroll
      for (int j=0;j<4;j++){
        int slot = tid + 256*j;
        int kb = slot>>6, nb = (slot&63)<<2;
        *(float4*)&Bs[g][kb][nb] = breg[g][j];
      }
    }
    __syncthreads();
    #pragma unroll
    for (int k=0;k<16;k++){
      #pragma unroll
      for (int g=0;g<NG;g++){
        float4 av = *(const float4*)&As[g][k][tm];
        float4 b0 = *(const float4*)&Bs[g][k][c0];
        float4 b1 = *(const float4*)&Bs[g][k][c0+128];
        float a_[4]={av.x,av.y,av.z,av.w};
        float b_[8]={b0.x,b0.y,b0.z,b0.w,b1.x,b1.y,b1.z,b1.w};
        #pragma unroll
        for (int i=0;i<4;i++)
          #pragma unroll
          for (int j=0;j<8;j++)
            acc[g][i][j] = fmaf(a_[i], b_[j], acc[g][i][j]);
      }
    }
  }

  #pragma unroll
  for (int i=0;i<4;i++){
    int m = bm + tm + i;
    if (m >= M) continue;
    #pragma unroll
    for (int half=0; half<2; half++){
      int c = c0 + half*128;
      float4 r;
      float* rr = &r.x;
      if (MODE==0){
        #pragma unroll
        for (int j=0;j<4;j++) rr[j] = acc[0][i][half*4+j];
      } else {
        float4 ft = feat_eval4(f1, m, c);
        float fv[4]={ft.x,ft.y,ft.z,ft.w};
        #pragma unroll
        for (int j=0;j<4;j++){
          float s = acc[0][i][half*4+j] + (NG>1?acc[1][i][half*4+j]:0.f) + fv[j];
          float v = (MODE==1)? fmaxf(s,0.f) : tanhf(s);
          if (MODE==1 && mask0 && m==0) v = 0.f;
          rr[j] = v;
        }
      }
      if (Cf)  *(float4*)(Cf  + (size_t)m*256+c) = r;
      if (Cf2) *(float4*)(Cf2 + (size_t)m*256+c) = r;
      if (Cb){
        uint2 p; p.x = pack2bf(r.x,r.y); p.y = pack2bf(r.z,r.w);
        *(uint2*)(Cb + (size_t)m*256+c) = p;
      }
    }
  }
}

// ---------------------------------------------------------------------------
extern "C" void kernel_launch(void* const* d_in, const int* in_sizes, int n_in,
                              void* d_out, int out_size, void* d_ws, size_t ws_size,
                              hipStream_t stream)
{
  const int* t_fnode  = (const int*)d_in[0];
  const int* t_fmess  = (const int*)d_in[1];
  const int* t_agraph = (const int*)d_in[2];
  const int* t_bgraph = (const int*)d_in[3];
  const int* t_cgraph = (const int*)d_in[4];
  const int* g_fnode  = (const int*)d_in[5];
  const int* g_fmess  = (const int*)d_in[6];
  const int* g_agraph = (const int*)d_in[7];
  const int* g_bgraph = (const int*)d_in[8];
  const int* roots    = (const int*)d_in[9];
  const float* E_c     = (const float*)d_in[10];
  const float* E_i     = (const float*)d_in[11];
  const float* Wc_w    = (const float*)d_in[12];
  const float* Wc_b    = (const float*)d_in[13];
  const float* Wi_w    = (const float*)d_in[14];
  const float* Wi_b    = (const float*)d_in[15];
  const float* Wroot_w = (const float*)d_in[16];
  const float* Wroot_b = (const float*)d_in[17];
  const float* t_Wo_w  = (const float*)d_in[18];
  const float* t_Wo_b  = (const float*)d_in[19];
  const float* t_Wz_w  = (const float*)d_in[20];
  const float* t_Wz_b  = (const float*)d_in[21];
  const float* t_Wr_w  = (const float*)d_in[22];
  const float* t_Ur_w  = (const float*)d_in[23];
  const float* t_Ur_b  = (const float*)d_in[24];
  const float* t_Wh_w  = (const float*)d_in[25];
  const float* t_Wh_b  = (const float*)d_in[26];
  const float* i_Wo_w  = (const float*)d_in[27];
  const float* i_Wo_b  = (const float*)d_in[28];
  const float* i_Wz_w  = (const float*)d_in[29];
  const float* i_Wz_b  = (const float*)d_in[30];
  const float* i_Wr_w  = (const float*)d_in[31];
  const float* i_Ur_w  = (const float*)d_in[32];
  const float* i_Ur_b  = (const float*)d_in[33];
  const float* i_Wh_w  = (const float*)d_in[34];
  const float* i_Wh_b  = (const float*)d_in[35];
  const float* g_Wo_w  = (const float*)d_in[36];
  const float* g_Wo_b  = (const float*)d_in[37];
  const float* g_Wz_w  = (const float*)d_in[38];
  const float* g_Wz_b  = (const float*)d_in[39];
  const float* g_Wr_w  = (const float*)d_in[40];
  const float* g_Ur_w  = (const float*)d_in[41];
  const float* g_Ur_b  = (const float*)d_in[42];
  const float* g_Wh_w  = (const float*)d_in[43];
  const float* g_Wh_b  = (const float*)d_in[44];

  float* out        = (float*)d_out;
  float* out_hroot  = out;
  float* out_htree  = out + (size_t)65536;
  float* out_hinter = out + (size_t)65536 + 2048000;
  float* out_hatom  = out + (size_t)65536 + 2048000 + 2048000;

  // ---- workspace (~156.2 MB) ----------------------------------------------
  char* base = (char*)d_ws;
  int*   aidx   = (int*)base;                              // 262144 B reserved
  short* planes = (short*)(base + 262144);                 // 18 x 65536 shorts
  float* hbuf   = (float*)(base + 262144 + 18*65536*2);    // 50000x256 f32
  float* sumh   = hbuf + (size_t)12800000;                 // 50000x256 f32
  bf16*  hUbuf  = (bf16*)(sumh + (size_t)12800000);        // 50000x256 bf16
  bf16*  sumgh  = hUbuf + (size_t)12800000;                // 50000x256 bf16

  auto P = [&](int i)->short* { return planes + (size_t)i*65536; };
  // per phase p: 0=Ur_hi 1=Ur_lo 2=Wzh_hi 3=Wzh_lo 4=Whh_hi 5=Whh_lo

  // non-GRU sub-buffers (lifetimes traced; GRU touches rows [0,M) of each plane)
  float* neibG    = sumh;                        // 25000 rows
  float* hatom    = sumh + (size_t)25000*256;    // 25000 rows
  float* neib_t   = hbuf;                        // 8000
  float* finb     = hbuf + (size_t)8000*256;     // 8000
  float* hn_i     = hbuf + (size_t)16000*256;    // 8000 (alive through I Wo)
  float* hnWz     = sumh + (size_t)16000*256;    // 8000
  float* hnWr     = sumh + (size_t)24000*256;    // 8000
  float* hnWh     = sumh + (size_t)32000*256;    // 8000
  float* nei_i    = sumh;                        // 8000 (post I-GRU)
  float* hinter   = sumh + (size_t)8000*256;     // 8000
  float* finb_c   = hbuf + (size_t)24000*256;    // 8000
  float* hn_t     = hbuf + (size_t)32000*256;    // 8000 (alive through root)
  float* nei_t    = sumh;                        // 8000 (post T-GRU)
  float* hn_roots = sumh + (size_t)8000*256;     // 256
  float* nei_root = sumh + (size_t)8256*256;     // 256

  (void)in_sizes; (void)n_in; (void)out_size; (void)ws_size;

  // ---- weight split/swizzle (once per call, 9 tiny kernels) ---------------
  k_splitw<<<256,256,0,stream>>>(g_Ur_w,                     P(0),  P(1));
  k_splitw<<<256,256,0,stream>>>(g_Wz_w + (size_t)64*256,    P(2),  P(3));
  k_splitw<<<256,256,0,stream>>>(g_Wh_w + (size_t)64*256,    P(4),  P(5));
  k_splitw<<<256,256,0,stream>>>(i_Ur_w,                     P(6),  P(7));
  k_splitw<<<256,256,0,stream>>>(i_Wz_w + (size_t)276*256,   P(8),  P(9));
  k_splitw<<<256,256,0,stream>>>(i_Wh_w + (size_t)276*256,   P(10), P(11));
  k_splitw<<<256,256,0,stream>>>(t_Ur_w,                     P(12), P(13));
  k_splitw<<<256,256,0,stream>>>(t_Wz_w + (size_t)276*256,   P(14), P(15));
  k_splitw<<<256,256,0,stream>>>(t_Wh_w + (size_t)276*256,   P(16), P(17));

  // ---- feature descriptors -------------------------------------------------
  Feat fzg{}; fzg.otab=g_Wz_w; fzg.oidx0=aidx;      fzg.os0=1; fzg.oo0=0;
              fzg.oidx1=g_fmess+2; fzg.os1=4; fzg.oo1=40;
              fzg.oidx2=g_fmess+3; fzg.os2=4; fzg.oo2=44; fzg.bias=g_Wz_b;
  Feat frg = fzg; frg.otab=g_Wr_w; frg.bias=g_Ur_b;
  Feat fhg = fzg; fhg.otab=g_Wh_w; fhg.bias=g_Wh_b;

  Feat fzi{}; fzi.dtab=hnWz; fzi.didx=t_fmess; fzi.dstride=3;
              fzi.otab=i_Wz_w; fzi.oidx0=t_fmess+2; fzi.os0=3; fzi.oo0=256; fzi.bias=i_Wz_b;
  Feat fri = fzi; fri.dtab=hnWr; fri.otab=i_Wr_w; fri.bias=i_Ur_b;
  Feat fhi = fzi; fhi.dtab=hnWh; fhi.otab=i_Wh_w; fhi.bias=i_Wh_b;

  Feat fzt = fzi; fzt.otab=t_Wz_w; fzt.bias=t_Wz_b;
  Feat frt = fri; frt.otab=t_Wr_w; frt.bias=t_Ur_b;
  Feat fht = fhi; fht.otab=t_Wh_w; fht.bias=t_Wh_b;

  Feat fnone{};

  // ---- GRU driver: step1 elementwise, then 4 x (hU, gather, GRU-mfma) ------
  auto run_gru = [&](int M, const int* bgraph, int p,
                     Feat fz, Feat fr, Feat fh)->float* {
    int gb32 = (M+31)/32, gb4 = (M+3)/4;
    k_step1<<<gb4,256,0,stream>>>(fz, fh, hbuf, M);
    for (int d=0; d<4; ++d){
      mfma_hU<<<gb32,256,0,stream>>>(hbuf, P(p*6+0), P(p*6+1), hUbuf, M);
      k_msg_gather<<<gb4,256,0,stream>>>(hbuf, hUbuf, bgraph, fr, sumh, sumgh, M);
      mfma_gru<<<gb32,256,0,stream>>>(sumh, sumgh, P(p*6+2), P(p*6+3),
                                      P(p*6+4), P(p*6+5), fz, fh, hbuf, M);
    }
    return hbuf;
  };

  // ==== Phase G: atom graph MPN ============================================
  k_aidx<<<(MA_+255)/256,256,0,stream>>>(g_fnode, g_fmess, aidx, MA_);
  float* hg = run_gru(MA_, g_bgraph, 0, fzg, frg, fhg);
  k_gsum4<<<(NA_+3)/4,256,0,stream>>>(hg, g_agraph, nullptr, 6, 6, neibG, NA_);
  Feat fWo{}; fWo.otab=g_Wo_w; fWo.oidx0=g_fnode; fWo.os0=1; fWo.oo0=0; fWo.bias=g_Wo_b;
  gemm256<1,1,0><<<(NA_+31)/32,256,0,stream>>>(neibG, g_Wo_w + (size_t)40*256,
      nullptr, nullptr, hatom, out_hatom, nullptr, NA_, fWo, fnone, 1);

  // ==== Phase I prep ========================================================
  k_gsum4<<<(NT_+3)/4,256,0,stream>>>(hatom, t_cgraph, nullptr, 12, 12, neib_t, NT_);
  k_gsum4<<<(NT_+3)/4,256,0,stream>>>(E_i, t_fnode+1, nullptr, 1, 2, finb, NT_);
  Feat fbWi{}; fbWi.bias=Wi_b;
  gemm256<2,1,0><<<NT_/32,256,0,stream>>>(finb, Wi_w, neib_t, Wi_w + (size_t)256*256,
      hn_i, nullptr, nullptr, NT_, fbWi, fnone, 0);
  gemm256<1,0,0><<<NT_/32,256,0,stream>>>(hn_i, i_Wz_w, nullptr,nullptr, hnWz, nullptr, nullptr, NT_, fnone, fnone, 0);
  gemm256<1,0,0><<<NT_/32,256,0,stream>>>(hn_i, i_Wr_w, nullptr,nullptr, hnWr, nullptr, nullptr, NT_, fnone, fnone, 0);
  gemm256<1,0,0><<<NT_/32,256,0,stream>>>(hn_i, i_Wh_w, nullptr,nullptr, hnWh, nullptr, nullptr, NT_, fnone, fnone, 0);

  // ==== Phase I GRU =========================================================
  float* hi = run_gru(MT_, t_bgraph, 1, fzi, fri, fhi);
  k_gsum4<<<(NT_+3)/4,256,0,stream>>>(hi, t_agraph, nullptr, 6, 6, nei_i, NT_);
  Feat fbWoi{}; fbWoi.bias=i_Wo_b;
  gemm256<2,1,0><<<NT_/32,256,0,stream>>>(hn_i, i_Wo_w, nei_i, i_Wo_w + (size_t)256*256,
      hinter, out_hinter, nullptr, NT_, fbWoi, fnone, 1);

  // ==== Phase T prep ========================================================
  k_gsum4<<<(NT_+3)/4,256,0,stream>>>(E_c, t_fnode+0, nullptr, 1, 2, finb_c, NT_);
  Feat fbWc{}; fbWc.bias=Wc_b;
  gemm256<2,1,0><<<NT_/32,256,0,stream>>>(finb_c, Wc_w, hinter, Wc_w + (size_t)256*256,
      hn_t, nullptr, nullptr, NT_, fbWc, fnone, 0);
  gemm256<1,0,0><<<NT_/32,256,0,stream>>>(hn_t, t_Wz_w, nullptr,nullptr, hnWz, nullptr, nullptr, NT_, fnone, fnone, 0);
  gemm256<1,0,0><<<NT_/32,256,0,stream>>>(hn_t, t_Wr_w, nullptr,nullptr, hnWr, nullptr, nullptr, NT_, fnone, fnone, 0);
  gemm256<1,0,0><<<NT_/32,256,0,stream>>>(hn_t, t_Wh_w, nullptr,nullptr, hnWh, nullptr, nullptr, NT_, fnone, fnone, 0);

  // ==== Phase T GRU =========================================================
  float* ht = run_gru(MT_, t_bgraph, 2, fzt, frt, fht);
  k_gsum4<<<(NT_+3)/4,256,0,stream>>>(ht, t_agraph, nullptr, 6, 6, nei_t, NT_);
  Feat fbWot{}; fbWot.bias=t_Wo_b;
  gemm256<2,1,0><<<NT_/32,256,0,stream>>>(hn_t, t_Wo_w, nei_t, t_Wo_w + (size_t)256*256,
      out_htree, nullptr, nullptr, NT_, fbWot, fnone, 1);

  // ==== Root ================================================================
  k_gsum4<<<(NROOT_+3)/4,256,0,stream>>>(hn_t, roots, nullptr, 1, 1, hn_roots, NROOT_);
  k_gsum4<<<(NROOT_+3)/4,256,0,stream>>>(ht, t_agraph, roots, 6, 6, nei_root, NROOT_);
  Feat fbWr{}; fbWr.bias=Wroot_b;
  gemm256<2,2,0><<<NROOT_/32,256,0,stream>>>(hn_roots, Wroot_w, nei_root,
      Wroot_w + (size_t)256*256, out_hroot, nullptr, nullptr, NROOT_, fbWr, fnone, 0);
}

// Round 7
// 2742.855 us; speedup vs baseline: 3.3780x; 1.3526x over previous
//
#include <hip/hip_runtime.h>
#include <hip/hip_bf16.h>
#include <math.h>

typedef __hip_bfloat16 bf16;
typedef __attribute__((ext_vector_type(8))) short  bf16x8;
typedef __attribute__((ext_vector_type(4))) float  f32x4;

#define NT_ 8000
#define MT_ 16000
#define NA_ 25000
#define MA_ 50000
#define NROOT_ 256

// ---------------------------------------------------------------------------
struct Feat {
  const float* dtab; const int* didx; int dstride;
  const float* otab;
  const int* oidx0; int os0; int oo0;
  const int* oidx1; int os1; int oo1;
  const int* oidx2; int os2; int oo2;
  const float* bias;
};

__device__ __forceinline__ float sigm(float x){ return 1.0f/(1.0f+expf(-x)); }
__device__ __forceinline__ float ubf(unsigned int u){ union{unsigned int i; float f;} x; x.i = u<<16; return x.f; }
__device__ __forceinline__ unsigned int pack2bf(float a, float b){
  bf16 x = __float2bfloat16(a), y = __float2bfloat16(b);
  unsigned short ux = *(unsigned short*)&x, uy = *(unsigned short*)&y;
  return (unsigned int)ux | ((unsigned int)uy<<16);
}
__device__ __forceinline__ short f2bf_s(float f){
  bf16 b = __float2bfloat16(f);
  return *(short*)&b;
}
__device__ __forceinline__ float bfs2f(short s){ return ubf((unsigned short)s); }

__device__ __forceinline__ void acc4(float4& v, const float* p){
  float4 t = *(const float4*)p;
  v.x+=t.x; v.y+=t.y; v.z+=t.z; v.w+=t.w;
}
__device__ __forceinline__ float4 feat_eval4(const Feat& f, int m, int n){
  float4 v = make_float4(0,0,0,0);
  if (f.bias) acc4(v, f.bias + n);
  if (f.dtab) acc4(v, f.dtab + (size_t)f.didx[(size_t)m*f.dstride]*256 + n);
  if (f.otab){
    acc4(v, f.otab + (size_t)(f.oidx0[(size_t)m*f.os0]+f.oo0)*256 + n);
    if (f.oidx1) acc4(v, f.otab + (size_t)(f.oidx1[(size_t)m*f.os1]+f.oo1)*256 + n);
    if (f.oidx2) acc4(v, f.otab + (size_t)(f.oidx2[(size_t)m*f.os2]+f.oo2)*256 + n);
  }
  return v;
}
__device__ __forceinline__ float feat_eval(const Feat& f, int m, int n){
  float v = 0.0f;
  if (f.bias) v += f.bias[n];
  if (f.dtab) v += f.dtab[(size_t)f.didx[(size_t)m*f.dstride]*256 + n];
  if (f.otab){
    v += f.otab[((size_t)(f.oidx0[(size_t)m*f.os0]+f.oo0))*256 + n];
    if (f.oidx1) v += f.otab[((size_t)(f.oidx1[(size_t)m*f.os1]+f.oo1))*256 + n];
    if (f.oidx2) v += f.otab[((size_t)(f.oidx2[(size_t)m*f.os2]+f.oo2))*256 + n];
  }
  return v;
}

// ---------------------------------------------------------------------------
__global__ void k_aidx(const int* __restrict__ g_fnode, const int* __restrict__ g_fmess,
                       int* __restrict__ aidx, int M){
  int m = blockIdx.x*blockDim.x + threadIdx.x;
  if (m<M) aidx[m] = g_fnode[g_fmess[(size_t)m*4]];
}

// 256x256 W -> MFMA-frag plane, hi/lo interleaved per lane (32B locality).
// tile=(k>>5)*16+(n>>4); lane=(n&15)+16*((k>>3)&3); j=k&7.
// dest: tile*1024 + lane*16 + j (hi), +8 (lo).
__global__ void k_splitw_i(const float* __restrict__ W, short* __restrict__ P){
  int idx = blockIdx.x*256 + threadIdx.x;   // 65536
  int k = idx>>8, n = idx&255;
  float w = W[idx];
  int base = (((k>>5)*16 + (n>>4))<<10) + (((n&15) + (((k>>3)&3)<<4))<<4) + (k&7);
  short h = f2bf_s(w);
  P[base]   = h;
  P[base+8] = f2bf_s(w - bfs2f(h));
}

// 64x256 W -> ext plane, hi/lo interleaved (32 tiles, 32768 shorts).
__global__ void k_splitw_ext(const float* __restrict__ W, short* __restrict__ P){
  int idx = blockIdx.x*256 + threadIdx.x;   // 16384
  int k = idx>>8, n = idx&255;
  float w = W[idx];
  int base = (((k>>5)*16 + (n>>4))<<10) + (((n&15) + (((k>>3)&3)<<4))<<4) + (k&7);
  short h = f2bf_s(w);
  P[base]   = h;
  P[base+8] = f2bf_s(w - bfs2f(h));
}

// GRU step 1 (h0 = 0): h1 = sigmoid(fz) * tanh(fh); row 0 zeroed.
__global__ void k_step1(Feat fz, Feat fh, float* __restrict__ h1, int M){
  int idx = blockIdx.x*256 + threadIdx.x;
  int m = idx>>6, c = (idx&63)<<2;
  if (m>=M) return;
  float4 z4 = feat_eval4(fz,m,c);
  float4 p4 = feat_eval4(fh,m,c);
  float4 v;
  v.x = sigm(z4.x)*tanhf(p4.x);
  v.y = sigm(z4.y)*tanhf(p4.y);
  v.z = sigm(z4.z)*tanhf(p4.z);
  v.w = sigm(z4.w)*tanhf(p4.w);
  if (m==0) v = make_float4(0,0,0,0);
  *(float4*)(h1 + (size_t)m*256 + c) = v;
}

// dst[m] = sum_j src[idx[(rowsel?rowsel[m]:m)*istride + j]]   (wave per row)
__global__ void k_gsum4(const float* __restrict__ src, const int* __restrict__ idx,
                        const int* __restrict__ rowsel, int J, int istride,
                        float* __restrict__ dst, int M){
  int wid = (blockIdx.x<<2) + (threadIdx.x>>6);
  if (wid>=M) return;
  int c = (threadIdx.x&63)<<2;
  int r = rowsel ? rowsel[wid] : wid;
  float4 s = make_float4(0,0,0,0);
  for (int j=0;j<J;j++){
    int id = idx[(size_t)r*istride+j];
    acc4(s, src + (size_t)id*256 + c);
  }
  *(float4*)(dst + (size_t)wid*256 + c) = s;
}

// Per message: sumh = sum_j h[bg[j]];  sumgh = sum_j sigmoid(fr + hU[bg[j]]) * h[bg[j]]
__global__ __launch_bounds__(256)
void k_msg_gather(const float* __restrict__ cur, const bf16* __restrict__ hU,
                  const int* __restrict__ bgraph, Feat fr,
                  float* __restrict__ sumh, bf16* __restrict__ sumgh, int M){
  int wid = (blockIdx.x<<2) + (threadIdx.x>>6);
  if (wid>=M) return;
  int c = (threadIdx.x&63)<<2;
  float4 fr4 = feat_eval4(fr, wid, c);
  const int* bg = bgraph + (size_t)wid*6;
  float4 s = make_float4(0,0,0,0);
  float4 g = make_float4(0,0,0,0);
  #pragma unroll
  for (int j=0;j<6;j++){
    int id = bg[j];
    float4 h4 = *(const float4*)(cur + (size_t)id*256 + c);
    uint2  u2 = *(const uint2*)(hU  + (size_t)id*256 + c);
    float u0=ubf(u2.x&0xffffu), u1=ubf(u2.x>>16), u2f=ubf(u2.y&0xffffu), u3=ubf(u2.y>>16);
    s.x+=h4.x; s.y+=h4.y; s.z+=h4.z; s.w+=h4.w;
    g.x += sigm(fr4.x+u0 )*h4.x;
    g.y += sigm(fr4.y+u1 )*h4.y;
    g.z += sigm(fr4.z+u2f)*h4.z;
    g.w += sigm(fr4.w+u3 )*h4.w;
  }
  *(float4*)(sumh + (size_t)wid*256 + c) = s;
  uint2 p; p.x = pack2bf(g.x,g.y); p.y = pack2bf(g.z,g.w);
  *(uint2*)(sumgh + (size_t)wid*256 + c) = p;
}

// ---------------------------------------------------------------------------
// MFMA kernels. Block = 256 thr = 4 waves; wave wc=tid>>6 covers cols
// [wc*64,+64) (4 tiles); block covers rows [bid*32,+32) as 2 A-frags.
// ---------------------------------------------------------------------------
__device__ __forceinline__ void build_a(const float* p, bf16x8& hi, bf16x8& lo){
  float4 v0 = *(const float4*)p;
  float4 v1 = *(const float4*)(p+4);
  float vv[8]={v0.x,v0.y,v0.z,v0.w,v1.x,v1.y,v1.z,v1.w};
  #pragma unroll
  for (int j=0;j<8;j++){
    short h = f2bf_s(vv[j]);
    hi[j]=h;
    lo[j]=f2bf_s(vv[j]-bfs2f(h));
  }
}

#define MFMA __builtin_amdgcn_mfma_f32_16x16x32_bf16

// out = A @ W (bf16x3). BFOUT: bf16 out (hU) else f32 out (hnW tables).
template<int BFOUT>
__global__ __launch_bounds__(256)
void mfma_mm(const float* __restrict__ A, const short* __restrict__ Bp,
             float* __restrict__ outf, bf16* __restrict__ outb, int M)
{
  const int tid=threadIdx.x, lane=tid&63, wc=tid>>6;
  const int rbase = blockIdx.x<<5;
  const int r0 = rbase + (lane&15), r1 = r0 + 16;
  const int koff = (lane>>4)<<3;
  f32x4 zero = {0.f,0.f,0.f,0.f};
  f32x4 acc[2][4];
  #pragma unroll
  for (int rf=0;rf<2;rf++)
    #pragma unroll
    for (int t=0;t<4;t++) acc[rf][t]=zero;

  for (int kc=0;kc<8;kc++){
    bf16x8 a0h={0,0,0,0,0,0,0,0}, a0l=a0h, a1h=a0h, a1l=a0h;
    if (r0<M) build_a(A + (size_t)r0*256 + kc*32 + koff, a0h, a0l);
    if (r1<M) build_a(A + (size_t)r1*256 + kc*32 + koff, a1h, a1l);
    #pragma unroll
    for (int t=0;t<4;t++){
      const short* p = Bp + (((kc<<4)+(wc<<2)+t)<<10) + (lane<<4);
      bf16x8 bh = *(const bf16x8*)p;
      bf16x8 bl = *(const bf16x8*)(p+8);
      acc[0][t]=MFMA(a0h,bh,acc[0][t],0,0,0);
      acc[1][t]=MFMA(a1h,bh,acc[1][t],0,0,0);
      acc[0][t]=MFMA(a0l,bh,acc[0][t],0,0,0);
      acc[1][t]=MFMA(a1l,bh,acc[1][t],0,0,0);
      acc[0][t]=MFMA(a0h,bl,acc[0][t],0,0,0);
      acc[1][t]=MFMA(a1h,bl,acc[1][t],0,0,0);
    }
  }
  const int rr = rbase + ((lane>>4)<<2);
  const int cl = lane&15;
  #pragma unroll
  for (int rf=0;rf<2;rf++)
    #pragma unroll
    for (int t=0;t<4;t++){
      int col = (((wc<<2)+t)<<4) + cl;
      #pragma unroll
      for (int r=0;r<4;r++){
        int m = rr + rf*16 + r;
        if (m>=M) continue;
        if (BFOUT) outb[(size_t)m*256+col] = __float2bfloat16(acc[rf][t][r]);
        else       outf[(size_t)m*256+col] = acc[rf][t][r];
      }
    }
}

// GRU step: z=sig(sumh@Wzh + fz); pre=tanh(sumgh@Whh + fh); h=(1-z)*sumh+z*pre.
// GEXT=1 (g-phase): fz/fh folded into K-ext one-hot MFMA chunks (hi+lo exact);
// epilogue adds bias only.  GEXT=0 (i/t): fz/fh via feat tables in epilogue.
template<int GEXT>
__global__ __launch_bounds__(256)
void mfma_gru(const float* __restrict__ sumh, const bf16* __restrict__ sumgh,
              const short* __restrict__ Bz, const short* __restrict__ Bh,
              const short* __restrict__ Bze, const short* __restrict__ Bhe,
              const int* __restrict__ aidx, const int* __restrict__ gfm,
              const float* __restrict__ bzb, const float* __restrict__ bhb,
              Feat fz, Feat fh, float* __restrict__ hout, int M)
{
  const int tid=threadIdx.x, lane=tid&63, wc=tid>>6;
  const int rbase = blockIdx.x<<5;
  const int r0 = rbase + (lane&15), r1 = r0 + 16;
  const int koff = (lane>>4)<<3;
  f32x4 zero = {0.f,0.f,0.f,0.f};
  f32x4 accz[2][4], acch[2][4];
  #pragma unroll
  for (int rf=0;rf<2;rf++)
    #pragma unroll
    for (int t=0;t<4;t++){ accz[rf][t]=zero; acch[rf][t]=zero; }

  for (int kc=0;kc<8;kc++){
    bf16x8 a0h={0,0,0,0,0,0,0,0}, a0l=a0h, a1h=a0h, a1l=a0h, s0=a0h, s1=a0h;
    if (r0<M){
      build_a(sumh + (size_t)r0*256 + kc*32 + koff, a0h, a0l);
      s0 = *(const bf16x8*)(const void*)(sumgh + (size_t)r0*256 + kc*32 + koff);
    }
    if (r1<M){
      build_a(sumh + (size_t)r1*256 + kc*32 + koff, a1h, a1l);
      s1 = *(const bf16x8*)(const void*)(sumgh + (size_t)r1*256 + kc*32 + koff);
    }
    #pragma unroll
    for (int t=0;t<4;t++){
      const short* pz = Bz + (((kc<<4)+(wc<<2)+t)<<10) + (lane<<4);
      const short* ph = Bh + (((kc<<4)+(wc<<2)+t)<<10) + (lane<<4);
      bf16x8 bzh = *(const bf16x8*)pz;
      bf16x8 bzl = *(const bf16x8*)(pz+8);
      bf16x8 bhh = *(const bf16x8*)ph;
      bf16x8 bhl = *(const bf16x8*)(ph+8);
      accz[0][t]=MFMA(a0h,bzh,accz[0][t],0,0,0);
      accz[1][t]=MFMA(a1h,bzh,accz[1][t],0,0,0);
      accz[0][t]=MFMA(a0l,bzh,accz[0][t],0,0,0);
      accz[1][t]=MFMA(a1l,bzh,accz[1][t],0,0,0);
      accz[0][t]=MFMA(a0h,bzl,accz[0][t],0,0,0);
      accz[1][t]=MFMA(a1h,bzl,accz[1][t],0,0,0);
      acch[0][t]=MFMA(s0,bhh,acch[0][t],0,0,0);
      acch[1][t]=MFMA(s1,bhh,acch[1][t],0,0,0);
      acch[0][t]=MFMA(s0,bhl,acch[0][t],0,0,0);
      acch[1][t]=MFMA(s1,bhl,acch[1][t],0,0,0);
    }
  }

  if (GEXT){
    int h0a=-1,h0b=-1,h0c=-1,h1a=-1,h1b=-1,h1c=-1;
    if (r0<M){ h0a=aidx[r0]; h0b=40+gfm[(size_t)r0*4+2]; h0c=44+gfm[(size_t)r0*4+3]; }
    if (r1<M){ h1a=aidx[r1]; h1b=40+gfm[(size_t)r1*4+2]; h1c=44+gfm[(size_t)r1*4+3]; }
    #pragma unroll
    for (int e=0;e<2;e++){
      bf16x8 ax0, ax1;
      #pragma unroll
      for (int j=0;j<8;j++){
        int d = e*32 + koff + j;
        ax0[j] = (d==h0a||d==h0b||d==h0c) ? (short)0x3F80 : (short)0;
        ax1[j] = (d==h1a||d==h1b||d==h1c) ? (short)0x3F80 : (short)0;
      }
      #pragma unroll
      for (int t=0;t<4;t++){
        const short* pe = Bze + (((e<<4)+(wc<<2)+t)<<10) + (lane<<4);
        const short* qe = Bhe + (((e<<4)+(wc<<2)+t)<<10) + (lane<<4);
        bf16x8 bzeh = *(const bf16x8*)pe;
        bf16x8 bzel = *(const bf16x8*)(pe+8);
        bf16x8 bheh = *(const bf16x8*)qe;
        bf16x8 bhel = *(const bf16x8*)(qe+8);
        accz[0][t]=MFMA(ax0,bzeh,accz[0][t],0,0,0);
        accz[1][t]=MFMA(ax1,bzeh,accz[1][t],0,0,0);
        accz[0][t]=MFMA(ax0,bzel,accz[0][t],0,0,0);
        accz[1][t]=MFMA(ax1,bzel,accz[1][t],0,0,0);
        acch[0][t]=MFMA(ax0,bheh,acch[0][t],0,0,0);
        acch[1][t]=MFMA(ax1,bheh,acch[1][t],0,0,0);
        acch[0][t]=MFMA(ax0,bhel,acch[0][t],0,0,0);
        acch[1][t]=MFMA(ax1,bhel,acch[1][t],0,0,0);
      }
    }
  }

  const int rr = rbase + ((lane>>4)<<2);
  const int cl = lane&15;
  #pragma unroll
  for (int rf=0;rf<2;rf++)
    #pragma unroll
    for (int t=0;t<4;t++){
      int col = (((wc<<2)+t)<<4) + cl;
      float fzb=0.f, fhb=0.f;
      if (GEXT){ fzb = bzb[col]; fhb = bhb[col]; }
      #pragma unroll
      for (int r=0;r<4;r++){
        int m = rr + rf*16 + r;
        if (m>=M) continue;
        float fzv = GEXT ? fzb : feat_eval(fz,m,col);
        float fhv = GEXT ? fhb : feat_eval(fh,m,col);
        float z   = sigm (accz[rf][t][r] + fzv);
        float pre = tanhf(acch[rf][t][r] + fhv);
        float sh  = sumh[(size_t)m*256+col];
        float v = (m==0) ? 0.f : ((1.f-z)*sh + z*pre);
        hout[(size_t)m*256+col] = v;
      }
    }
}

// ---------------------------------------------------------------------------
// Vector GEMM (round-4 proven) for the remaining projections.
// ---------------------------------------------------------------------------
template<int NG, int MODE, int A2BF>
__global__ __launch_bounds__(256)
void gemm256(const float* __restrict__ A1, const float* __restrict__ B1,
             const void* __restrict__ A2v, const float* __restrict__ B2,
             float* __restrict__ Cf, float* __restrict__ Cf2,
             bf16* __restrict__ Cb, int M,
             Feat f1, Feat f2, int mask0)
{
  __shared__ float As[NG][16][36];
  __shared__ float Bs[NG][16][260];
  const int tid = threadIdx.x;
  const int bm = blockIdx.x<<5;
  const int tm = (tid>>5)<<2;
  const int c0 = (tid&31)<<2;

  float acc[NG][4][8];
  #pragma unroll
  for (int g=0;g<NG;g++)
    #pragma unroll
    for (int i=0;i<4;i++)
      #pragma unroll
      for (int j=0;j<8;j++) acc[g][i][j]=0.f;

  const int t7  = tid & 127;
  const int alm = t7>>2;
  const int alk = (t7&3)<<2;
  const int arow = bm + alm;
  const int amat = (NG==2)? (tid>>7) : 0;
  const bool astage = (NG==2) || (tid<128);
  const bf16*  A2b = (const bf16*)A2v;
  const float* A2f = (const float*)A2v;

  for (int k0=0;k0<256;k0+=16){
    float a0=0,a1=0,a2=0,a3=0;
    if (astage && arow<M){
      if (A2BF && amat==1){
        uint2 u = *(const uint2*)(A2b + (size_t)arow*256 + k0 + alk);
        a0=ubf(u.x&0xffffu); a1=ubf(u.x>>16); a2=ubf(u.y&0xffffu); a3=ubf(u.y>>16);
      } else {
        const float* src = (amat==0)? A1 : A2f;
        float4 v = *(const float4*)(src + (size_t)arow*256 + k0 + alk);
        a0=v.x; a1=v.y; a2=v.z; a3=v.w;
      }
    }
    float4 breg[NG][4];
    #pragma unroll
    for (int g=0; g<NG; g++){
      const float* B = (g==0)? B1 : B2;
      #pragma unroll
      for (int j=0;j<4;j++){
        int slot = tid + 256*j;
        int kb = slot>>6, nb = (slot&63)<<2;
        breg[g][j] = *(const float4*)(B + (size_t)(k0+kb)*256 + nb);
      }
    }
    __syncthreads();
    if (astage){
      As[amat][alk+0][alm]=a0; As[amat][alk+1][alm]=a1;
      As[amat][alk+2][alm]=a2; As[amat][alk+3][alm]=a3;
    }
    #pragma unroll
    for (int g=0; g<NG; g++){
      #pragma unroll
      for (int j=0;j<4;j++){
        int slot = tid + 256*j;
        int kb = slot>>6, nb = (slot&63)<<2;
        *(float4*)&Bs[g][kb][nb] = breg[g][j];
      }
    }
    __syncthreads();
    #pragma unroll
    for (int k=0;k<16;k++){
      #pragma unroll
      for (int g=0;g<NG;g++){
        float4 av = *(const float4*)&As[g][k][tm];
        float4 b0 = *(const float4*)&Bs[g][k][c0];
        float4 b1 = *(const float4*)&Bs[g][k][c0+128];
        float a_[4]={av.x,av.y,av.z,av.w};
        float b_[8]={b0.x,b0.y,b0.z,b0.w,b1.x,b1.y,b1.z,b1.w};
        #pragma unroll
        for (int i=0;i<4;i++)
          #pragma unroll
          for (int j=0;j<8;j++)
            acc[g][i][j] = fmaf(a_[i], b_[j], acc[g][i][j]);
      }
    }
  }

  #pragma unroll
  for (int i=0;i<4;i++){
    int m = bm + tm + i;
    if (m >= M) continue;
    #pragma unroll
    for (int half=0; half<2; half++){
      int c = c0 + half*128;
      float4 r;
      float* rr = &r.x;
      if (MODE==0){
        #pragma unroll
        for (int j=0;j<4;j++) rr[j] = acc[0][i][half*4+j];
      } else {
        float4 ft = feat_eval4(f1, m, c);
        float fv[4]={ft.x,ft.y,ft.z,ft.w};
        #pragma unroll
        for (int j=0;j<4;j++){
          float s = acc[0][i][half*4+j] + (NG>1?acc[1][i][half*4+j]:0.f) + fv[j];
          float v = (MODE==1)? fmaxf(s,0.f) : tanhf(s);
          if (MODE==1 && mask0 && m==0) v = 0.f;
          rr[j] = v;
        }
      }
      if (Cf)  *(float4*)(Cf  + (size_t)m*256+c) = r;
      if (Cf2) *(float4*)(Cf2 + (size_t)m*256+c) = r;
      if (Cb){
        uint2 p; p.x = pack2bf(r.x,r.y); p.y = pack2bf(r.z,r.w);
        *(uint2*)(Cb + (size_t)m*256+c) = p;
      }
    }
  }
}

// ---------------------------------------------------------------------------
extern "C" void kernel_launch(void* const* d_in, const int* in_sizes, int n_in,
                              void* d_out, int out_size, void* d_ws, size_t ws_size,
                              hipStream_t stream)
{
  const int* t_fnode  = (const int*)d_in[0];
  const int* t_fmess  = (const int*)d_in[1];
  const int* t_agraph = (const int*)d_in[2];
  const int* t_bgraph = (const int*)d_in[3];
  const int* t_cgraph = (const int*)d_in[4];
  const int* g_fnode  = (const int*)d_in[5];
  const int* g_fmess  = (const int*)d_in[6];
  const int* g_agraph = (const int*)d_in[7];
  const int* g_bgraph = (const int*)d_in[8];
  const int* roots    = (const int*)d_in[9];
  const float* E_c     = (const float*)d_in[10];
  const float* E_i     = (const float*)d_in[11];
  const float* Wc_w    = (const float*)d_in[12];
  const float* Wc_b    = (const float*)d_in[13];
  const float* Wi_w    = (const float*)d_in[14];
  const float* Wi_b    = (const float*)d_in[15];
  const float* Wroot_w = (const float*)d_in[16];
  const float* Wroot_b = (const float*)d_in[17];
  const float* t_Wo_w  = (const float*)d_in[18];
  const float* t_Wo_b  = (const float*)d_in[19];
  const float* t_Wz_w  = (const float*)d_in[20];
  const float* t_Wz_b  = (const float*)d_in[21];
  const float* t_Wr_w  = (const float*)d_in[22];
  const float* t_Ur_w  = (const float*)d_in[23];
  const float* t_Ur_b  = (const float*)d_in[24];
  const float* t_Wh_w  = (const float*)d_in[25];
  const float* t_Wh_b  = (const float*)d_in[26];
  const float* i_Wo_w  = (const float*)d_in[27];
  const float* i_Wo_b  = (const float*)d_in[28];
  const float* i_Wz_w  = (const float*)d_in[29];
  const float* i_Wz_b  = (const float*)d_in[30];
  const float* i_Wr_w  = (const float*)d_in[31];
  const float* i_Ur_w  = (const float*)d_in[32];
  const float* i_Ur_b  = (const float*)d_in[33];
  const float* i_Wh_w  = (const float*)d_in[34];
  const float* i_Wh_b  = (const float*)d_in[35];
  const float* g_Wo_w  = (const float*)d_in[36];
  const float* g_Wo_b  = (const float*)d_in[37];
  const float* g_Wz_w  = (const float*)d_in[38];
  const float* g_Wz_b  = (const float*)d_in[39];
  const float* g_Wr_w  = (const float*)d_in[40];
  const float* g_Ur_w  = (const float*)d_in[41];
  const float* g_Ur_b  = (const float*)d_in[42];
  const float* g_Wh_w  = (const float*)d_in[43];
  const float* g_Wh_b  = (const float*)d_in[44];

  float* out        = (float*)d_out;
  float* out_hroot  = out;
  float* out_htree  = out + (size_t)65536;
  float* out_hinter = out + (size_t)65536 + 2048000;
  float* out_hatom  = out + (size_t)65536 + 2048000 + 2048000;

  // ---- workspace (~158 MB) -------------------------------------------------
  char* base = (char*)d_ws;
  int*   aidx   = (int*)base;                              // 262144 B reserved
  short* SP     = (short*)(base + 262144);                 // plane region (4 MB)
  float* hbuf   = (float*)(base + 262144 + 4194304);       // 50000x256 f32
  float* sumh   = hbuf + (size_t)12800000;                 // 50000x256 f32
  bf16*  hUbuf  = (bf16*)(sumh + (size_t)12800000);        // 50000x256 bf16
  bf16*  sumgh  = hUbuf + (size_t)12800000;                // 50000x256 bf16

  // GRU planes (interleaved hi/lo): phase p in {0,1,2}: Ur=p*3+0, Wz=p*3+1, Wh=p*3+2
  auto GP = [&](int i)->short* { return SP + (size_t)i*131072; };
  short* EZ = SP + (size_t)9*131072;          // g ext Wz (32768 shorts, hi/lo)
  short* EH = EZ + 32768;                     // g ext Wh
  auto HP = [&](int j)->short* { return EH + 32768 + (size_t)j*131072; }; // 6 hnW planes
  // total: 1179648 + 65536 + 786432 = 2031616 shorts <= 2097152 (4 MB)

  // non-GRU sub-buffers (lifetimes as in round 5)
  float* neibG    = sumh;                        // 25000 rows
  float* hatom    = sumh + (size_t)25000*256;    // 25000 rows
  float* neib_t   = hbuf;                        // 8000
  float* finb     = hbuf + (size_t)8000*256;     // 8000
  float* hn_i     = hbuf + (size_t)16000*256;    // 8000 (alive through I Wo)
  float* hnWz     = sumh + (size_t)16000*256;    // 8000
  float* hnWr     = sumh + (size_t)24000*256;    // 8000
  float* hnWh     = sumh + (size_t)32000*256;    // 8000
  float* nei_i    = sumh;                        // 8000 (post I-GRU)
  float* hinter   = sumh + (size_t)8000*256;     // 8000
  float* finb_c   = hbuf + (size_t)24000*256;    // 8000
  float* hn_t     = hbuf + (size_t)32000*256;    // 8000 (alive through root)
  float* nei_t    = sumh;                        // 8000 (post T-GRU)
  float* hn_roots = sumh + (size_t)8000*256;     // 256
  float* nei_root = sumh + (size_t)8256*256;     // 256

  (void)in_sizes; (void)n_in; (void)out_size; (void)ws_size;

  // ---- weight split/swizzle (once per call) --------------------------------
  k_splitw_i<<<256,256,0,stream>>>(g_Ur_w,                     GP(0));
  k_splitw_i<<<256,256,0,stream>>>(g_Wz_w + (size_t)64*256,    GP(1));
  k_splitw_i<<<256,256,0,stream>>>(g_Wh_w + (size_t)64*256,    GP(2));
  k_splitw_i<<<256,256,0,stream>>>(i_Ur_w,                     GP(3));
  k_splitw_i<<<256,256,0,stream>>>(i_Wz_w + (size_t)276*256,   GP(4));
  k_splitw_i<<<256,256,0,stream>>>(i_Wh_w + (size_t)276*256,   GP(5));
  k_splitw_i<<<256,256,0,stream>>>(t_Ur_w,                     GP(6));
  k_splitw_i<<<256,256,0,stream>>>(t_Wz_w + (size_t)276*256,   GP(7));
  k_splitw_i<<<256,256,0,stream>>>(t_Wh_w + (size_t)276*256,   GP(8));
  k_splitw_ext<<<64,256,0,stream>>>(g_Wz_w, EZ);
  k_splitw_ext<<<64,256,0,stream>>>(g_Wh_w, EH);
  k_splitw_i<<<256,256,0,stream>>>(i_Wz_w, HP(0));
  k_splitw_i<<<256,256,0,stream>>>(i_Wr_w, HP(1));
  k_splitw_i<<<256,256,0,stream>>>(i_Wh_w, HP(2));
  k_splitw_i<<<256,256,0,stream>>>(t_Wz_w, HP(3));
  k_splitw_i<<<256,256,0,stream>>>(t_Wr_w, HP(4));
  k_splitw_i<<<256,256,0,stream>>>(t_Wh_w, HP(5));

  // ---- feature descriptors -------------------------------------------------
  Feat fzg{}; fzg.otab=g_Wz_w; fzg.oidx0=aidx;      fzg.os0=1; fzg.oo0=0;
              fzg.oidx1=g_fmess+2; fzg.os1=4; fzg.oo1=40;
              fzg.oidx2=g_fmess+3; fzg.os2=4; fzg.oo2=44; fzg.bias=g_Wz_b;
  Feat frg = fzg; frg.otab=g_Wr_w; frg.bias=g_Ur_b;
  Feat fhg = fzg; fhg.otab=g_Wh_w; fhg.bias=g_Wh_b;

  Feat fzi{}; fzi.dtab=hnWz; fzi.didx=t_fmess; fzi.dstride=3;
              fzi.otab=i_Wz_w; fzi.oidx0=t_fmess+2; fzi.os0=3; fzi.oo0=256; fzi.bias=i_Wz_b;
  Feat fri = fzi; fri.dtab=hnWr; fri.otab=i_Wr_w; fri.bias=i_Ur_b;
  Feat fhi = fzi; fhi.dtab=hnWh; fhi.otab=i_Wh_w; fhi.bias=i_Wh_b;

  Feat fzt = fzi; fzt.otab=t_Wz_w; fzt.bias=t_Wz_b;
  Feat frt = fri; frt.otab=t_Wr_w; frt.bias=t_Ur_b;
  Feat fht = fhi; fht.otab=t_Wh_w; fht.bias=t_Wh_b;

  Feat fnone{};

  // ---- GRU driver ----------------------------------------------------------
  auto run_gru = [&](int M, const int* bgraph, int p, bool gext,
                     Feat fz, Feat fr, Feat fh)->float* {
    int gb32 = (M+31)/32, gb4 = (M+3)/4;
    k_step1<<<gb4,256,0,stream>>>(fz, fh, hbuf, M);
    for (int d=0; d<4; ++d){
      mfma_mm<1><<<gb32,256,0,stream>>>(hbuf, GP(p*3+0), nullptr, hUbuf, M);
      k_msg_gather<<<gb4,256,0,stream>>>(hbuf, hUbuf, bgraph, fr, sumh, sumgh, M);
      if (gext)
        mfma_gru<1><<<gb32,256,0,stream>>>(sumh, sumgh, GP(p*3+1), GP(p*3+2),
            EZ, EH, aidx, g_fmess, g_Wz_b, g_Wh_b, fnone, fnone, hbuf, M);
      else
        mfma_gru<0><<<gb32,256,0,stream>>>(sumh, sumgh, GP(p*3+1), GP(p*3+2),
            nullptr, nullptr, nullptr, nullptr, nullptr, nullptr, fz, fh, hbuf, M);
    }
    return hbuf;
  };

  // ==== Phase G: atom graph MPN ============================================
  k_aidx<<<(MA_+255)/256,256,0,stream>>>(g_fnode, g_fmess, aidx, MA_);
  float* hg = run_gru(MA_, g_bgraph, 0, true, fzg, frg, fhg);
  k_gsum4<<<(NA_+3)/4,256,0,stream>>>(hg, g_agraph, nullptr, 6, 6, neibG, NA_);
  Feat fWo{}; fWo.otab=g_Wo_w; fWo.oidx0=g_fnode; fWo.os0=1; fWo.oo0=0; fWo.bias=g_Wo_b;
  gemm256<1,1,0><<<(NA_+31)/32,256,0,stream>>>(neibG, g_Wo_w + (size_t)40*256,
      nullptr, nullptr, hatom, out_hatom, nullptr, NA_, fWo, fnone, 1);

  // ==== Phase I prep ========================================================
  k_gsum4<<<(NT_+3)/4,256,0,stream>>>(hatom, t_cgraph, nullptr, 12, 12, neib_t, NT_);
  k_gsum4<<<(NT_+3)/4,256,0,stream>>>(E_i, t_fnode+1, nullptr, 1, 2, finb, NT_);
  Feat fbWi{}; fbWi.bias=Wi_b;
  gemm256<2,1,0><<<NT_/32,256,0,stream>>>(finb, Wi_w, neib_t, Wi_w + (size_t)256*256,
      hn_i, nullptr, nullptr, NT_, fbWi, fnone, 0);
  mfma_mm<0><<<NT_/32,256,0,stream>>>(hn_i, HP(0), hnWz, nullptr, NT_);
  mfma_mm<0><<<NT_/32,256,0,stream>>>(hn_i, HP(1), hnWr, nullptr, NT_);
  mfma_mm<0><<<NT_/32,256,0,stream>>>(hn_i, HP(2), hnWh, nullptr, NT_);

  // ==== Phase I GRU =========================================================
  float* hi = run_gru(MT_, t_bgraph, 1, false, fzi, fri, fhi);
  k_gsum4<<<(NT_+3)/4,256,0,stream>>>(hi, t_agraph, nullptr, 6, 6, nei_i, NT_);
  Feat fbWoi{}; fbWoi.bias=i_Wo_b;
  gemm256<2,1,0><<<NT_/32,256,0,stream>>>(hn_i, i_Wo_w, nei_i, i_Wo_w + (size_t)256*256,
      hinter, out_hinter, nullptr, NT_, fbWoi, fnone, 1);

  // ==== Phase T prep ========================================================
  k_gsum4<<<(NT_+3)/4,256,0,stream>>>(E_c, t_fnode+0, nullptr, 1, 2, finb_c, NT_);
  Feat fbWc{}; fbWc.bias=Wc_b;
  gemm256<2,1,0><<<NT_/32,256,0,stream>>>(finb_c, Wc_w, hinter, Wc_w + (size_t)256*256,
      hn_t, nullptr, nullptr, NT_, fbWc, fnone, 0);
  mfma_mm<0><<<NT_/32,256,0,stream>>>(hn_t, HP(3), hnWz, nullptr, NT_);
  mfma_mm<0><<<NT_/32,256,0,stream>>>(hn_t, HP(4), hnWr, nullptr, NT_);
  mfma_mm<0><<<NT_/32,256,0,stream>>>(hn_t, HP(5), hnWh, nullptr, NT_);

  // ==== Phase T GRU =========================================================
  float* ht = run_gru(MT_, t_bgraph, 2, false, fzt, frt, fht);
  k_gsum4<<<(NT_+3)/4,256,0,stream>>>(ht, t_agraph, nullptr, 6, 6, nei_t, NT_);
  Feat fbWot{}; fbWot.bias=t_Wo_b;
  gemm256<2,1,0><<<NT_/32,256,0,stream>>>(hn_t, t_Wo_w, nei_t, t_Wo_w + (size_t)256*256,
      out_htree, nullptr, nullptr, NT_, fbWot, fnone, 1);

  // ==== Root ================================================================
  k_gsum4<<<(NROOT_+3)/4,256,0,stream>>>(hn_t, roots, nullptr, 1, 1, hn_roots, NROOT_);
  k_gsum4<<<(NROOT_+3)/4,256,0,stream>>>(ht, t_agraph, roots, 6, 6, nei_root, NROOT_);
  Feat fbWr{}; fbWr.bias=Wroot_b;
  gemm256<2,2,0><<<NROOT_/32,256,0,stream>>>(hn_roots, Wroot_w, nei_root,
      Wroot_w + (size_t)256*256, out_hroot, nullptr, nullptr, NROOT_, fbWr, fnone, 0);
}